// Round 1
// baseline (520.287 us; speedup 1.0000x reference)
//
#include <hip/hip_runtime.h>

#define LSEQ 8192
#define NFFT 16384
#define NTH  1024
#define DCH  768

__device__ __forceinline__ float2 cmul(float2 a, float2 b) {
    return make_float2(fmaf(a.x, b.x, -(a.y * b.y)), fmaf(a.x, b.y, a.y * b.x));
}
__device__ __forceinline__ float2 cadd(float2 a, float2 b) { return make_float2(a.x + b.x, a.y + b.y); }
__device__ __forceinline__ float2 csub(float2 a, float2 b) { return make_float2(a.x - b.x, a.y - b.y); }

// base-4 digit reversal of a 14-bit index (7 digits); involution
__device__ __forceinline__ int drev14(int v) {
    int r = 0;
#pragma unroll
    for (int i = 0; i < 7; ++i) { r = (r << 2) | (v & 3); v >>= 2; }
    return r;
}

extern "C" __global__ void __launch_bounds__(NTH)
fftconv_kernel(const float* __restrict__ hg, const float* __restrict__ xg,
               const float* __restrict__ bg, float* __restrict__ yg) {
    extern __shared__ float2 z[];   // NFFT complex, 128 KiB

    const int tid = threadIdx.x;
    const int bid = blockIdx.x;
    const int d = bid >> 2;    // channel
    const int b = bid & 3;     // batch

    const float4* x4 = (const float4*)(xg + ((size_t)(b * DCH + d)) * LSEQ);
    const float4* h4 = (const float4*)(hg + (size_t)d * LSEQ);

    // ---- load: z[t] = x[t] + i*h[t] for t<L, zero-pad to 2L ----
    float4 xv0, xv1;
    {
        float4 hq;
        const int i0 = tid, i1 = tid + NTH;      // float4 indices, 2048/row
        xv0 = x4[i0]; hq = h4[i0];
        int t = i0 * 4;
        z[t + 0] = make_float2(xv0.x, hq.x);
        z[t + 1] = make_float2(xv0.y, hq.y);
        z[t + 2] = make_float2(xv0.z, hq.z);
        z[t + 3] = make_float2(xv0.w, hq.w);
        xv1 = x4[i1]; hq = h4[i1];
        t = i1 * 4;
        z[t + 0] = make_float2(xv1.x, hq.x);
        z[t + 1] = make_float2(xv1.y, hq.y);
        z[t + 2] = make_float2(xv1.z, hq.z);
        z[t + 3] = make_float2(xv1.w, hq.w);
        const float2 zero = make_float2(0.f, 0.f);
        t = LSEQ + i0 * 4;
        z[t + 0] = zero; z[t + 1] = zero; z[t + 2] = zero; z[t + 3] = zero;
        t = LSEQ + i1 * 4;
        z[t + 0] = zero; z[t + 1] = zero; z[t + 2] = zero; z[t + 3] = zero;
    }
    __syncthreads();

    // ---- forward complex FFT, radix-4 DIF, in-place, natural -> digit-reversed ----
    for (int lm = 12; lm >= 0; lm -= 2) {           // m = 4096 .. 1
        const int m = 1 << lm;
        // -1/(4m): exact power-of-two reciprocal via exponent bits
        const float nrev = -__uint_as_float((unsigned)(127 - (lm + 2)) << 23);
#pragma unroll
        for (int q = 0; q < (NFFT / 4) / NTH; ++q) { // 4 butterflies / thread
            const int w = tid + q * NTH;
            const int j = w & (m - 1);
            const int i0 = ((w >> lm) << (lm + 2)) + j;
            float2 a0 = z[i0], a1 = z[i0 + m], a2 = z[i0 + 2 * m], a3 = z[i0 + 3 * m];
            float2 t0 = cadd(a0, a2), t1 = cadd(a1, a3);
            float2 t2 = csub(a0, a2), t3 = csub(a1, a3);
            const float rev = (float)j * nrev;       // revolutions: -j/(4m)
            const float s = __builtin_amdgcn_sinf(rev);
            const float c = __builtin_amdgcn_cosf(rev);
            const float2 w1 = make_float2(c, s);
            const float2 w2 = cmul(w1, w1);
            const float2 w3 = cmul(w2, w1);
            const float2 mi3 = make_float2(t3.y, -t3.x);   // -i * t3
            z[i0]         = cadd(t0, t1);
            z[i0 + m]     = cmul(cadd(t2, mi3), w1);
            z[i0 + 2 * m] = cmul(csub(t0, t1), w2);
            z[i0 + 3 * m] = cmul(csub(t2, mi3), w3);
        }
        __syncthreads();
    }

    // ---- pointwise: separate X,H from packed spectrum; P = X*H (digit-reversed domain) ----
#pragma unroll
    for (int q = 0; q < LSEQ / NTH; ++q) {           // k = 0 .. 8191
        const int k = tid + q * NTH;
        if (k == 0) {
            // DC: X0=Re(Z0), H0=Im(Z0)
            float2 z0 = z[0];
            z[0] = make_float2(z0.x * z0.y, 0.f);
            // Nyquist k=8192 lives at position drev(8192)=2
            float2 zn = z[2];
            z[2] = make_float2(zn.x * zn.y, 0.f);
        } else {
            const int p  = drev14(k);
            const int pp = drev14(NFFT - k);
            const float2 Zp = z[p], Zm = z[pp];
            const float2 A  = make_float2(Zp.x + Zm.x, Zp.y - Zm.y);  // Z[k] + conj(Z[N-k])
            const float2 Dv = make_float2(Zp.x - Zm.x, Zp.y + Zm.y);  // Z[k] - conj(Z[N-k])
            const float2 X  = make_float2(0.5f * A.x, 0.5f * A.y);
            const float2 H  = make_float2(0.5f * Dv.y, -0.5f * Dv.x); // -i/2 * Dv
            const float2 P  = cmul(X, H);
            z[p]  = P;
            z[pp] = make_float2(P.x, -P.y);                           // Hermitian partner
        }
    }
    __syncthreads();

    // ---- inverse complex FFT, radix-4 DIT, in-place, digit-reversed -> natural ----
    // (algebraic inverse of each DIF stage, conjugate twiddles; net scale N handled at store)
    for (int lm = 0; lm <= 12; lm += 2) {            // m = 1 .. 4096
        const int m = 1 << lm;
        const float prev = __uint_as_float((unsigned)(127 - (lm + 2)) << 23); // +1/(4m)
#pragma unroll
        for (int q = 0; q < (NFFT / 4) / NTH; ++q) {
            const int w = tid + q * NTH;
            const int j = w & (m - 1);
            const int i0 = ((w >> lm) << (lm + 2)) + j;
            float2 b0 = z[i0], b1 = z[i0 + m], b2 = z[i0 + 2 * m], b3 = z[i0 + 3 * m];
            const float rev = (float)j * prev;       // revolutions: +j/(4m)
            const float s = __builtin_amdgcn_sinf(rev);
            const float c = __builtin_amdgcn_cosf(rev);
            const float2 w1 = make_float2(c, s);
            const float2 w2 = cmul(w1, w1);
            const float2 w3 = cmul(w2, w1);
            const float2 v1 = cmul(b1, w1);
            const float2 v2 = cmul(b2, w2);
            const float2 v3 = cmul(b3, w3);
            const float2 t0 = cadd(b0, v2), t1 = csub(b0, v2);
            const float2 t2 = cadd(v1, v3);
            const float2 dd = csub(v3, v1);
            const float2 t3 = make_float2(dd.y, -dd.x);   // -i*(v3-v1)
            z[i0]         = cadd(t0, t2);
            z[i0 + m]     = cadd(t1, t3);
            z[i0 + 2 * m] = csub(t0, t2);
            z[i0 + 3 * m] = csub(t1, t3);
        }
        __syncthreads();
    }

    // ---- store: y = Re(ifft)/N + x*B[d] ----
    const float bd = bg[d];
    const float invN = 1.0f / (float)NFFT;
    float4* y4 = (float4*)(yg + ((size_t)(b * DCH + d)) * LSEQ);
    {
        const int i0 = tid, i1 = tid + NTH;
        float4 r;
        int t = i0 * 4;
        r.x = fmaf(xv0.x, bd, z[t + 0].x * invN);
        r.y = fmaf(xv0.y, bd, z[t + 1].x * invN);
        r.z = fmaf(xv0.z, bd, z[t + 2].x * invN);
        r.w = fmaf(xv0.w, bd, z[t + 3].x * invN);
        y4[i0] = r;
        t = i1 * 4;
        r.x = fmaf(xv1.x, bd, z[t + 0].x * invN);
        r.y = fmaf(xv1.y, bd, z[t + 1].x * invN);
        r.z = fmaf(xv1.z, bd, z[t + 2].x * invN);
        r.w = fmaf(xv1.w, bd, z[t + 3].x * invN);
        y4[i1] = r;
    }
}

extern "C" void kernel_launch(void* const* d_in, const int* in_sizes, int n_in,
                              void* d_out, int out_size, void* d_ws, size_t ws_size,
                              hipStream_t stream) {
    (void)in_sizes; (void)n_in; (void)d_ws; (void)ws_size; (void)out_size;
    const float* h = (const float*)d_in[0];
    const float* x = (const float*)d_in[1];
    const float* B = (const float*)d_in[2];
    float* y = (float*)d_out;

    // 128 KiB dynamic LDS (gfx950 has 160 KiB/CU); opt in defensively.
    (void)hipFuncSetAttribute((const void*)fftconv_kernel,
                              hipFuncAttributeMaxDynamicSharedMemorySize,
                              NFFT * (int)sizeof(float2));

    fftconv_kernel<<<dim3(4 * DCH), dim3(NTH), NFFT * sizeof(float2), stream>>>(h, x, B, y);
}

// Round 2
// 217.557 us; speedup vs baseline: 2.3915x; 2.3915x over previous
//
#include <hip/hip_runtime.h>

#define LSEQ 8192
#define NFFT 16384
#define NTH  1024
#define DCH  768
#define PHYS(i) ((i) + ((i) >> 4))
#define LDS_ELEMS (NFFT + NFFT / 16)   // 17408 float2 = 136 KiB

__device__ __forceinline__ float2 cmul(float2 a, float2 b) {
    return make_float2(fmaf(a.x, b.x, -(a.y * b.y)), fmaf(a.x, b.y, a.y * b.x));
}
__device__ __forceinline__ float2 cadd(float2 a, float2 b) { return make_float2(a.x + b.x, a.y + b.y); }
__device__ __forceinline__ float2 csub(float2 a, float2 b) { return make_float2(a.x - b.x, a.y - b.y); }
__device__ __forceinline__ float2 wtw(float rev) {      // e^{2*pi*i*rev}, |rev| < 1
    return make_float2(__builtin_amdgcn_cosf(rev), __builtin_amdgcn_sinf(rev));
}

// base-4 digit reversal, 7 digits (14 bits)
__device__ __forceinline__ int drev14(int v) {
    int r = 0;
#pragma unroll
    for (int i = 0; i < 7; ++i) { r = (r << 2) | (v & 3); v >>= 2; }
    return r;
}
// base-4 digit reversal, 5 digits (10 bits)
__device__ __forceinline__ int drev10(int v) {
    int r = 0;
#pragma unroll
    for (int i = 0; i < 5; ++i) { r = (r << 2) | (v & 3); v >>= 2; }
    return r;
}

// Fused DIF radix-16 (levels m1=4*m2 then m2) on a[16]; a[t] holds pos i0 + t*m2.
// r1 = -j/(16*m2), j = i0 mod m2.
__device__ __forceinline__ void dif16(float2* a, float r1) {
#pragma unroll
    for (int ai = 0; ai < 4; ++ai) {
        float2 u0 = a[ai], u1 = a[ai + 4], u2 = a[ai + 8], u3 = a[ai + 12];
        float2 t0 = cadd(u0, u2), t1 = cadd(u1, u3);
        float2 t2 = csub(u0, u2), t3 = csub(u1, u3);
        float2 mi3 = make_float2(t3.y, -t3.x);          // -i*t3
        float2 w1 = wtw(r1 - 0.0625f * ai);
        float2 w2 = cmul(w1, w1), w3 = cmul(w2, w1);
        a[ai]      = cadd(t0, t1);
        a[ai + 4]  = cmul(cadd(t2, mi3), w1);
        a[ai + 8]  = cmul(csub(t0, t1), w2);
        a[ai + 12] = cmul(csub(t2, mi3), w3);
    }
    float2 v1 = wtw(4.0f * r1);
    float2 v2 = cmul(v1, v1), v3 = cmul(v2, v1);
#pragma unroll
    for (int p = 0; p < 4; ++p) {
        float2 u0 = a[4 * p], u1 = a[4 * p + 1], u2 = a[4 * p + 2], u3 = a[4 * p + 3];
        float2 t0 = cadd(u0, u2), t1 = cadd(u1, u3);
        float2 t2 = csub(u0, u2), t3 = csub(u1, u3);
        float2 mi3 = make_float2(t3.y, -t3.x);
        a[4 * p]     = cadd(t0, t1);
        a[4 * p + 1] = cmul(cadd(t2, mi3), v1);
        a[4 * p + 2] = cmul(csub(t0, t1), v2);
        a[4 * p + 3] = cmul(csub(t2, mi3), v3);
    }
}

// Fused DIT radix-16 (levels m2 then m1=4*m2) on a[16]. r1 = +j/(16*m2).
__device__ __forceinline__ void dit16(float2* a, float r1) {
    float2 v1 = wtw(4.0f * r1);
    float2 v2 = cmul(v1, v1), v3 = cmul(v2, v1);
#pragma unroll
    for (int p = 0; p < 4; ++p) {
        float2 b0 = a[4 * p];
        float2 b1 = cmul(a[4 * p + 1], v1);
        float2 b2 = cmul(a[4 * p + 2], v2);
        float2 b3 = cmul(a[4 * p + 3], v3);
        float2 t0 = cadd(b0, b2), t1 = csub(b0, b2);
        float2 t2 = cadd(b1, b3);
        float2 dd = csub(b3, b1);
        float2 t3 = make_float2(dd.y, -dd.x);           // -i*(b3w3 - b1w1)
        a[4 * p]     = cadd(t0, t2);
        a[4 * p + 1] = cadd(t1, t3);
        a[4 * p + 2] = csub(t0, t2);
        a[4 * p + 3] = csub(t1, t3);
    }
#pragma unroll
    for (int ai = 0; ai < 4; ++ai) {
        float2 w1 = wtw(r1 + 0.0625f * ai);
        float2 w2 = cmul(w1, w1), w3 = cmul(w2, w1);
        float2 b0 = a[ai];
        float2 b1 = cmul(a[ai + 4], w1);
        float2 b2 = cmul(a[ai + 8], w2);
        float2 b3 = cmul(a[ai + 12], w3);
        float2 t0 = cadd(b0, b2), t1 = csub(b0, b2);
        float2 t2 = cadd(b1, b3);
        float2 dd = csub(b3, b1);
        float2 t3 = make_float2(dd.y, -dd.x);
        a[ai]      = cadd(t0, t2);
        a[ai + 4]  = cadd(t1, t3);
        a[ai + 8]  = csub(t0, t2);
        a[ai + 12] = csub(t1, t3);
    }
}

extern "C" __global__ void __launch_bounds__(NTH, 4)
fftconv_kernel(const float* __restrict__ hg, const float* __restrict__ xg,
               const float* __restrict__ bg, float* __restrict__ yg) {
    extern __shared__ float2 z[];
    const int w = threadIdx.x;
    const int bid = blockIdx.x;
    const int d = bid >> 2, b = bid & 3;
    const float* xr = xg + (size_t)(b * DCH + d) * LSEQ;
    const float* hr = hg + (size_t)d * LSEQ;

    float2 a[16];
    float xv[8];

    // ---- P1: global load + fused radix-16 (m2=1024), top half of z is zero ----
    {
#pragma unroll
        for (int t = 0; t < 8; ++t) {
            xv[t] = xr[w + 1024 * t];
            float hv = hr[w + 1024 * t];
            a[t] = make_float2(xv[t], hv);
        }
        const float r1 = -(float)w * (1.0f / 16384.0f);
        // level m1=4096 with inputs 2,3 == 0
#pragma unroll
        for (int ai = 0; ai < 4; ++ai) {
            float2 u0 = a[ai], u1 = a[ai + 4];
            float2 mi3 = make_float2(u1.y, -u1.x);      // -i*u1
            float2 w1 = wtw(r1 - 0.0625f * ai);
            float2 w2 = cmul(w1, w1), w3 = cmul(w2, w1);
            a[ai]      = cadd(u0, u1);
            a[ai + 4]  = cmul(cadd(u0, mi3), w1);
            a[ai + 8]  = cmul(csub(u0, u1), w2);
            a[ai + 12] = cmul(csub(u0, mi3), w3);
        }
        // level m2=1024 (full)
        float2 v1 = wtw(4.0f * r1);
        float2 v2 = cmul(v1, v1), v3 = cmul(v2, v1);
#pragma unroll
        for (int p = 0; p < 4; ++p) {
            float2 u0 = a[4 * p], u1 = a[4 * p + 1], u2 = a[4 * p + 2], u3 = a[4 * p + 3];
            float2 t0 = cadd(u0, u2), t1 = cadd(u1, u3);
            float2 t2 = csub(u0, u2), t3 = csub(u1, u3);
            float2 mi3 = make_float2(t3.y, -t3.x);
            a[4 * p]     = cadd(t0, t1);
            a[4 * p + 1] = cmul(cadd(t2, mi3), v1);
            a[4 * p + 2] = cmul(csub(t0, t1), v2);
            a[4 * p + 3] = cmul(csub(t2, mi3), v3);
        }
        const int base = PHYS(w);                        // PHYS(w + 1024t) = base + 1088t
#pragma unroll
        for (int t = 0; t < 16; ++t) z[base + 1088 * t] = a[t];
    }
    __syncthreads();

    // ---- P2: fused radix-16, m2 = 64 ----
    {
        const int j = w & 63, grp = w >> 6;
        const int base = PHYS(grp * 1024 + j);           // stride 68 in t
#pragma unroll
        for (int t = 0; t < 16; ++t) a[t] = z[base + 68 * t];
        dif16(a, -(float)j * (1.0f / 1024.0f));
#pragma unroll
        for (int t = 0; t < 16; ++t) z[base + 68 * t] = a[t];
    }
    __syncthreads();

    // ---- P3: fused radix-16, m2 = 4 ----
    {
        const int j = w & 3, grp = w >> 2;
        const int i0 = grp * 64 + j;
#pragma unroll
        for (int t = 0; t < 16; ++t) a[t] = z[PHYS(i0 + 4 * t)];
        dif16(a, -(float)j * (1.0f / 64.0f));
#pragma unroll
        for (int t = 0; t < 16; ++t) z[PHYS(i0 + 4 * t)] = a[t];
    }
    __syncthreads();

    // ---- P4: final radix-4 (m=1) + pointwise (Hermitian split) + inverse radix-4 (m=1) ----
    {
        const int base = 17 * w;                         // PHYS(16w + t) = 17w + t
#pragma unroll
        for (int t = 0; t < 16; ++t) a[t] = z[base + t];
#pragma unroll
        for (int u = 0; u < 4; ++u) {                    // forward m=1, twiddle-free
            float2 u0 = a[4 * u], u1 = a[4 * u + 1], u2 = a[4 * u + 2], u3 = a[4 * u + 3];
            float2 t0 = cadd(u0, u2), t1 = cadd(u1, u3);
            float2 t2 = csub(u0, u2), t3 = csub(u1, u3);
            float2 mi3 = make_float2(t3.y, -t3.x);
            a[4 * u]     = cadd(t0, t1);
            a[4 * u + 1] = cadd(t2, mi3);
            a[4 * u + 2] = csub(t0, t1);
            a[4 * u + 3] = csub(t2, mi3);
        }
#pragma unroll
        for (int t = 0; t < 16; ++t) z[base + t] = a[t]; // publish spectrum for partners
        __syncthreads();

        const int kw = drev10(w);
#pragma unroll
        for (int t = 0; t < 16; ++t) {
            const int rt = (((t & 3) << 2) | (t >> 2));  // 2-digit base-4 reversal of t
            const int k = (rt << 10) | kw;               // natural freq of own position p=16w+t
            const int pp = drev14(16384 - k);            // partner position (k=0/8192 degenerate->self)
            const float2 Zm = z[PHYS(pp)];
            const float2 Zp = a[t];
            const float2 A  = make_float2(Zp.x + Zm.x, Zp.y - Zm.y);
            const float2 Dv = make_float2(Zp.x - Zm.x, Zp.y + Zm.y);
            const float2 X  = make_float2(0.5f * A.x, 0.5f * A.y);
            const float2 H  = make_float2(0.5f * Dv.y, -0.5f * Dv.x);
            a[t] = cmul(X, H);
        }
        __syncthreads();                                 // all partner reads done before overwrite

#pragma unroll
        for (int u = 0; u < 4; ++u) {                    // inverse m=1, twiddle-free
            float2 b0 = a[4 * u], b1 = a[4 * u + 1], b2 = a[4 * u + 2], b3 = a[4 * u + 3];
            float2 t0 = cadd(b0, b2), t1 = csub(b0, b2);
            float2 t2 = cadd(b1, b3);
            float2 dd = csub(b3, b1);
            float2 t3 = make_float2(dd.y, -dd.x);
            a[4 * u]     = cadd(t0, t2);
            a[4 * u + 1] = cadd(t1, t3);
            a[4 * u + 2] = csub(t0, t2);
            a[4 * u + 3] = csub(t1, t3);
        }
#pragma unroll
        for (int t = 0; t < 16; ++t) z[base + t] = a[t];
    }
    __syncthreads();

    // ---- P5: fused DIT radix-16, m2 = 4 ----
    {
        const int j = w & 3, grp = w >> 2;
        const int i0 = grp * 64 + j;
#pragma unroll
        for (int t = 0; t < 16; ++t) a[t] = z[PHYS(i0 + 4 * t)];
        dit16(a, (float)j * (1.0f / 64.0f));
#pragma unroll
        for (int t = 0; t < 16; ++t) z[PHYS(i0 + 4 * t)] = a[t];
    }
    __syncthreads();

    // ---- P6: fused DIT radix-16, m2 = 64 ----
    {
        const int j = w & 63, grp = w >> 6;
        const int base = PHYS(grp * 1024 + j);
#pragma unroll
        for (int t = 0; t < 16; ++t) a[t] = z[base + 68 * t];
        dit16(a, (float)j * (1.0f / 1024.0f));
#pragma unroll
        for (int t = 0; t < 16; ++t) z[base + 68 * t] = a[t];
    }
    __syncthreads();

    // ---- P7: fused DIT (m2=1024, m1=4096), keep only outputs t<8, store y ----
    {
        const int base = PHYS(w);
#pragma unroll
        for (int t = 0; t < 16; ++t) a[t] = z[base + 1088 * t];
        const float r1 = (float)w * (1.0f / 16384.0f);
        // level m=1024 (full)
        float2 v1 = wtw(4.0f * r1);
        float2 v2 = cmul(v1, v1), v3 = cmul(v2, v1);
#pragma unroll
        for (int p = 0; p < 4; ++p) {
            float2 b0 = a[4 * p];
            float2 b1 = cmul(a[4 * p + 1], v1);
            float2 b2 = cmul(a[4 * p + 2], v2);
            float2 b3 = cmul(a[4 * p + 3], v3);
            float2 t0 = cadd(b0, b2), t1 = csub(b0, b2);
            float2 t2 = cadd(b1, b3);
            float2 dd = csub(b3, b1);
            float2 t3 = make_float2(dd.y, -dd.x);
            a[4 * p]     = cadd(t0, t2);
            a[4 * p + 1] = cadd(t1, t3);
            a[4 * p + 2] = csub(t0, t2);
            a[4 * p + 3] = csub(t1, t3);
        }
        // level m=4096: only outputs b=0,1 (positions < 8192) are needed
        const float bd = bg[d];
        const float invN = 1.0f / (float)NFFT;
#pragma unroll
        for (int ai = 0; ai < 4; ++ai) {
            float2 w1 = wtw(r1 + 0.0625f * ai);
            float2 w2 = cmul(w1, w1), w3 = cmul(w2, w1);
            float2 b0 = a[ai];
            float2 vv1 = cmul(a[ai + 4], w1);
            float2 vv2 = cmul(a[ai + 8], w2);
            float2 vv3 = cmul(a[ai + 12], w3);
            float2 t0 = cadd(b0, vv2), t1 = csub(b0, vv2);
            float2 t2 = cadd(vv1, vv3);
            float2 dd = csub(vv3, vv1);
            float2 t3 = make_float2(dd.y, -dd.x);
            float2 o0 = cadd(t0, t2);                    // position w + 1024*ai
            float2 o1 = cadd(t1, t3);                    // position w + 4096 + 1024*ai
            yg[(size_t)(b * DCH + d) * LSEQ + w + 1024 * ai]        = fmaf(xv[ai], bd, o0.x * invN);
            yg[(size_t)(b * DCH + d) * LSEQ + w + 4096 + 1024 * ai] = fmaf(xv[ai + 4], bd, o1.x * invN);
        }
    }
}

extern "C" void kernel_launch(void* const* d_in, const int* in_sizes, int n_in,
                              void* d_out, int out_size, void* d_ws, size_t ws_size,
                              hipStream_t stream) {
    (void)in_sizes; (void)n_in; (void)d_ws; (void)ws_size; (void)out_size;
    const float* h = (const float*)d_in[0];
    const float* x = (const float*)d_in[1];
    const float* B = (const float*)d_in[2];
    float* y = (float*)d_out;

    (void)hipFuncSetAttribute((const void*)fftconv_kernel,
                              hipFuncAttributeMaxDynamicSharedMemorySize,
                              LDS_ELEMS * (int)sizeof(float2));

    fftconv_kernel<<<dim3(4 * DCH), dim3(NTH), LDS_ELEMS * sizeof(float2), stream>>>(h, x, B, y);
}

// Round 3
// 140.772 us; speedup vs baseline: 3.6960x; 1.5455x over previous
//
#include <hip/hip_runtime.h>

#define DCH   768
#define NHALF 8192
#define NTH   512
#define PHYS(i) ((i) + ((i) >> 4))
#define LDSE  (NHALF + NHALF / 16)     // 8704 float2 = 69632 B
#define NFULL 16384
#define NTH2  1024
#define LDSE2 (NFULL + NFULL / 16)     // 17408 float2 = 139264 B

__device__ __forceinline__ float2 cmul(float2 a, float2 b) {
    return make_float2(fmaf(a.x, b.x, -(a.y * b.y)), fmaf(a.x, b.y, a.y * b.x));
}
__device__ __forceinline__ float2 cadd(float2 a, float2 b) { return make_float2(a.x + b.x, a.y + b.y); }
__device__ __forceinline__ float2 csub(float2 a, float2 b) { return make_float2(a.x - b.x, a.y - b.y); }
__device__ __forceinline__ float2 wtw(float rev) {   // e^{2*pi*i*rev}
    return make_float2(__builtin_amdgcn_cosf(rev), __builtin_amdgcn_sinf(rev));
}
__device__ __forceinline__ int drev8(int v) {        // 4-digit base-4 reversal of 8-bit
    return ((v & 3) << 6) | ((v & 12) << 2) | ((v >> 2) & 12) | ((v >> 6) & 3);
}
__device__ __forceinline__ constexpr int rev2i(int a) { return ((a & 3) << 2) | ((a >> 2) & 3); }
__device__ __forceinline__ constexpr int rtof(int t)  { return ((t & 3) << 2) | (t >> 2); }

__device__ __forceinline__ float2 Ktw(int rt) {      // e^{-2*pi*i*rt/32}
    const float KC[16] = {1.0f, 0.980785280f, 0.923879533f, 0.831469612f,
                          0.707106781f, 0.555570233f, 0.382683432f, 0.195090322f,
                          0.0f, -0.195090322f, -0.382683432f, -0.555570233f,
                          -0.707106781f, -0.831469612f, -0.923879533f, -0.980785280f};
    const float KS[16] = {0.0f, -0.195090322f, -0.382683432f, -0.555570233f,
                          -0.707106781f, -0.831469612f, -0.923879533f, -0.980785280f,
                          -1.0f, -0.980785280f, -0.923879533f, -0.831469612f,
                          -0.707106781f, -0.555570233f, -0.382683432f, -0.195090322f};
    return make_float2(KC[rt], KS[rt]);
}

// -------- fused radix-16 (two radix-4 DIF levels m1=4*m2 then m2); r1 = -j/(16*m2)
__device__ __forceinline__ void dif16(float2* a, float r1) {
#pragma unroll
    for (int ai = 0; ai < 4; ++ai) {
        float2 u0 = a[ai], u1 = a[ai + 4], u2 = a[ai + 8], u3 = a[ai + 12];
        float2 t0 = cadd(u0, u2), t1 = cadd(u1, u3);
        float2 t2 = csub(u0, u2), t3 = csub(u1, u3);
        float2 mi3 = make_float2(t3.y, -t3.x);
        float2 w1 = wtw(r1 - 0.0625f * ai);
        float2 w2 = cmul(w1, w1), w3 = cmul(w2, w1);
        a[ai]      = cadd(t0, t1);
        a[ai + 4]  = cmul(cadd(t2, mi3), w1);
        a[ai + 8]  = cmul(csub(t0, t1), w2);
        a[ai + 12] = cmul(csub(t2, mi3), w3);
    }
    float2 v1 = wtw(4.0f * r1);
    float2 v2 = cmul(v1, v1), v3 = cmul(v2, v1);
#pragma unroll
    for (int p = 0; p < 4; ++p) {
        float2 u0 = a[4 * p], u1 = a[4 * p + 1], u2 = a[4 * p + 2], u3 = a[4 * p + 3];
        float2 t0 = cadd(u0, u2), t1 = cadd(u1, u3);
        float2 t2 = csub(u0, u2), t3 = csub(u1, u3);
        float2 mi3 = make_float2(t3.y, -t3.x);
        a[4 * p]     = cadd(t0, t1);
        a[4 * p + 1] = cmul(cadd(t2, mi3), v1);
        a[4 * p + 2] = cmul(csub(t0, t1), v2);
        a[4 * p + 3] = cmul(csub(t2, mi3), v3);
    }
}
// -------- fused inverse radix-16 (levels m2 then m1=4*m2); r1 = +j/(16*m2)
__device__ __forceinline__ void dit16(float2* a, float r1) {
    float2 v1 = wtw(4.0f * r1);
    float2 v2 = cmul(v1, v1), v3 = cmul(v2, v1);
#pragma unroll
    for (int p = 0; p < 4; ++p) {
        float2 b0 = a[4 * p];
        float2 b1 = cmul(a[4 * p + 1], v1);
        float2 b2 = cmul(a[4 * p + 2], v2);
        float2 b3 = cmul(a[4 * p + 3], v3);
        float2 t0 = cadd(b0, b2), t1 = csub(b0, b2);
        float2 t2 = cadd(b1, b3);
        float2 dd = csub(b3, b1);
        float2 t3 = make_float2(dd.y, -dd.x);
        a[4 * p]     = cadd(t0, t2);
        a[4 * p + 1] = cadd(t1, t3);
        a[4 * p + 2] = csub(t0, t2);
        a[4 * p + 3] = csub(t1, t3);
    }
#pragma unroll
    for (int ai = 0; ai < 4; ++ai) {
        float2 w1 = wtw(r1 + 0.0625f * ai);
        float2 w2 = cmul(w1, w1), w3 = cmul(w2, w1);
        float2 b0 = a[ai];
        float2 b1 = cmul(a[ai + 4], w1);
        float2 b2 = cmul(a[ai + 8], w2);
        float2 b3 = cmul(a[ai + 12], w3);
        float2 t0 = cadd(b0, b2), t1 = csub(b0, b2);
        float2 t2 = cadd(b1, b3);
        float2 dd = csub(b3, b1);
        float2 t3 = make_float2(dd.y, -dd.x);
        a[ai]      = cadd(t0, t2);
        a[ai + 4]  = cadd(t1, t3);
        a[ai + 8]  = csub(t0, t2);
        a[ai + 12] = csub(t1, t3);
    }
}
__device__ __forceinline__ void fwd4x4(float2* a) {   // radix-4 DIF, m=1, twiddle-free
#pragma unroll
    for (int u = 0; u < 4; ++u) {
        float2 u0 = a[4*u], u1 = a[4*u+1], u2 = a[4*u+2], u3 = a[4*u+3];
        float2 t0 = cadd(u0, u2), t1 = cadd(u1, u3), t2 = csub(u0, u2), t3 = csub(u1, u3);
        float2 mi3 = make_float2(t3.y, -t3.x);
        a[4*u] = cadd(t0, t1); a[4*u+1] = cadd(t2, mi3);
        a[4*u+2] = csub(t0, t1); a[4*u+3] = csub(t2, mi3);
    }
}
__device__ __forceinline__ void inv4x4(float2* a) {   // inverse radix-4, m=1
#pragma unroll
    for (int u = 0; u < 4; ++u) {
        float2 b0 = a[4*u], b1 = a[4*u+1], b2 = a[4*u+2], b3 = a[4*u+3];
        float2 t0 = cadd(b0, b2), t1 = csub(b0, b2), t2 = cadd(b1, b3);
        float2 dd = csub(b3, b1);
        float2 t3 = make_float2(dd.y, -dd.x);
        a[4*u] = cadd(t0, t2); a[4*u+1] = cadd(t1, t3);
        a[4*u+2] = csub(t0, t2); a[4*u+3] = csub(t1, t3);
    }
}

// Forward 8192-pt complex FFT of src (4096 nonzero float2, top half zero),
// DIF levels [2@4096, 4@1024 | 4@256, 4@64 | 4@16, 4@4 | 4@1].
// On return: z holds C in scrambled order, a[16] holds thread's own 16 values
// (positions 16w + t).
__device__ __forceinline__ void fwd8k(const float2* __restrict__ src,
                                      float2* __restrict__ z, const int w, float2* a) {
    const float R2 = 0.70710678118654752f;
    // ---- P1: radix-2(m=4096, top half zero) + radix-4(m=1024) from global
#pragma unroll
    for (int g = 0; g < 2; ++g) {
        const int i0 = w + 512 * g;
        float2 c0 = src[i0], c1 = src[i0 + 1024], c2 = src[i0 + 2048], c3 = src[i0 + 3072];
        const float2 wA  = wtw(-(float)i0 * (1.0f / 8192.0f));
        const float2 wB  = cmul(wA, wA);
        const float2 wB2 = cmul(wB, wB);
        const float2 wB3 = cmul(wB2, wB);
        const int pb = PHYS(i0);
        // top block: stage-A output = c[t]
        float2 t0 = cadd(c0, c2), t1 = cadd(c1, c3), t2 = csub(c0, c2), t3 = csub(c1, c3);
        float2 mi3 = make_float2(t3.y, -t3.x);
        z[pb]            = cadd(t0, t1);
        z[pb + 1088]     = cmul(cadd(t2, mi3), wB);
        z[pb + 2 * 1088] = cmul(csub(t0, t1), wB2);
        z[pb + 3 * 1088] = cmul(csub(t2, mi3), wB3);
        // bottom block: stage-A output = c[t]*wA*e^{-2pi i t/8}
        float2 d0 = cmul(c0, wA);
        float2 d1 = cmul(c1, cmul(wA, make_float2(R2, -R2)));
        float2 d2 = cmul(c2, make_float2(wA.y, -wA.x));           // -i*wA
        float2 d3 = cmul(c3, cmul(wA, make_float2(-R2, -R2)));
        t0 = cadd(d0, d2); t1 = cadd(d1, d3); t2 = csub(d0, d2); t3 = csub(d1, d3);
        mi3 = make_float2(t3.y, -t3.x);
        z[pb + 4 * 1088] = cadd(t0, t1);
        z[pb + 5 * 1088] = cmul(cadd(t2, mi3), wB);
        z[pb + 6 * 1088] = cmul(csub(t0, t1), wB2);
        z[pb + 7 * 1088] = cmul(csub(t2, mi3), wB3);
    }
    __syncthreads();
    // ---- P2: radix-16, m2 = 64
    {
        const int j = w & 63, blk = w >> 6;
        const int base = PHYS(blk * 1024 + j);
#pragma unroll
        for (int t = 0; t < 16; ++t) a[t] = z[base + 68 * t];
        dif16(a, -(float)j * (1.0f / 1024.0f));
#pragma unroll
        for (int t = 0; t < 16; ++t) z[base + 68 * t] = a[t];
    }
    __syncthreads();
    // ---- P3: radix-16, m2 = 4
    {
        const int j = w & 3, g = w >> 2;
        const int i0 = g * 64 + j;
#pragma unroll
        for (int t = 0; t < 16; ++t) a[t] = z[PHYS(i0 + 4 * t)];
        dif16(a, -(float)j * (1.0f / 64.0f));
#pragma unroll
        for (int t = 0; t < 16; ++t) z[PHYS(i0 + 4 * t)] = a[t];
    }
    __syncthreads();
    // ---- P4a: final radix-4 (m=1) in regs, publish C
    {
        const int base = 17 * w;
#pragma unroll
        for (int t = 0; t < 16; ++t) a[t] = z[base + t];
        fwd4x4(a);
#pragma unroll
        for (int t = 0; t < 16; ++t) z[base + t] = a[t];
    }
    __syncthreads();
}

// ============ kernel 1: per-channel H spectrum (scrambled, hidx layout), H += B
extern "C" __global__ void __launch_bounds__(NTH, 4)
hspec_kernel(const float* __restrict__ hg, const float* __restrict__ bg,
             float* __restrict__ wsHf, float* __restrict__ wsNy) {
    extern __shared__ float2 z[];
    const int w = threadIdx.x;
    const int d = blockIdx.x;
    const float2* hr = (const float2*)hg + (size_t)d * 4096;
    float2 a[16];
    fwd8k(hr, z, w, a);

    const float Bd = bg[d];
    float2* out = (float2*)wsHf + (size_t)d * NHALF;
    const int wm = w & 255, whi = w >> 8;
    const int k0 = 2 * drev8(wm) + whi;
    const float2 wk0 = wtw(-(float)k0 * (1.0f / 16384.0f));
    int qm = 0;
    if (w != 0) { const int bq = (512 - k0) >> 1; qm = (whi << 8) | drev8(bq); }
#pragma unroll
    for (int t = 0; t < 16; ++t) {
        const int rt = rtof(t);
        if (w == 0 && t == 0) {
            float2 C0 = a[0];
            out[0] = make_float2(C0.x + C0.y + Bd, 0.0f);
            ((float2*)wsNy)[d] = make_float2(C0.x - C0.y + Bd, 0.0f);
        } else {
            const int cq = (w == 0) ? rev2i(16 - rt) : rev2i(15 - rt);
            const float2 Cq = z[17 * qm + cq];
            const float2 Cp = a[t];
            const float2 cA = make_float2(0.5f * (Cp.x + Cq.x), 0.5f * (Cp.y - Cq.y));
            const float2 cB = make_float2(0.5f * (Cp.y + Cq.y), -0.5f * (Cp.x - Cq.x));
            const float2 Wk = cmul(wk0, Ktw(rt));
            const float2 Hf = cadd(cA, cmul(Wk, cB));
            out[(t << 9) + w] = make_float2(Hf.x + Bd, Hf.y);   // hidx(p)=(t<<9)|w
        }
    }
}

// ============ kernel 2: main conv
extern "C" __global__ void __launch_bounds__(NTH, 4)
fftconv_main(const float* __restrict__ xg, const float* __restrict__ wsHf,
             const float* __restrict__ wsNy, float* __restrict__ yg) {
    extern __shared__ float2 z[];
    const int w = threadIdx.x;
    const int bid = blockIdx.x;
    const int d = bid >> 2, b = bid & 3;
    const float2* xr = (const float2*)xg + (size_t)(b * DCH + d) * 4096;
    const float2* hrow = (const float2*)wsHf + (size_t)d * NHALF;
    const float R2 = 0.70710678118654752f;
    float2 a[16];
    fwd8k(xr, z, w, a);

    // ---- P4b: pair-owner combine: X from packed C, Y=X*H, repack to Wtil
    {
        const int wm = w & 255, whi = w >> 8;
        const int k0 = 2 * drev8(wm) + whi;
        const float2 wk0 = wtw(-(float)k0 * (1.0f / 16384.0f));
        int qm = 0;
        if (w != 0) { const int bq = (512 - k0) >> 1; qm = (whi << 8) | drev8(bq); }
#pragma unroll
        for (int t = 0; t < 16; ++t) {
            if ((t & 3) > 1) continue;           // owner elements: rt < 8
            const int rt = rtof(t);
            if (w == 0 && t == 0) {
                // DC + Nyquist of the 16K rfft
                float2 C0 = a[0];
                float X0 = C0.x + C0.y, XN = C0.x - C0.y;
                float2 H0 = hrow[0];
                float2 HN = ((const float2*)wsNy)[d];
                float2 Y1 = make_float2(X0 * H0.x, X0 * H0.y);
                float2 Y2 = make_float2(XN * HN.x, XN * HN.y);
                float2 S  = make_float2(Y1.x + Y2.x, Y1.y - Y2.y);
                float2 Dd = make_float2(Y1.x - Y2.x, Y1.y + Y2.y);
                z[0] = make_float2(S.x - Dd.y, S.y + Dd.x);      // V^0 = 1
            } else {
                const int cq = (w == 0) ? rev2i(16 - rt) : rev2i(15 - rt);
                const float2 Cq = z[17 * qm + cq];
                const float2 Cp = a[t];
                const float2 cA = make_float2(0.5f * (Cp.x + Cq.x), 0.5f * (Cp.y - Cq.y));
                const float2 cB = make_float2(0.5f * (Cp.y + Cq.y), -0.5f * (Cp.x - Cq.x));
                const float2 Wk = cmul(wk0, Ktw(rt));
                const float2 T  = cmul(Wk, cB);
                const float2 X1 = cadd(cA, T);
                const float2 X2 = make_float2(cA.x - T.x, -(cA.y - T.y));  // conj(cA - T)
                const float2 Hp = hrow[(t << 9) + w];
                const float2 Hq = hrow[(cq << 9) + qm];
                const float2 Y1 = cmul(X1, Hp);
                const float2 Y2 = cmul(X2, Hq);
                const float2 S  = make_float2(Y1.x + Y2.x, Y1.y - Y2.y);
                const float2 Dd = make_float2(Y1.x - Y2.x, Y1.y + Y2.y);
                const float2 Vk = make_float2(Wk.x, -Wk.y);
                const float2 U  = cmul(Vk, Dd);
                z[17 * w + t]     = make_float2(S.x - U.y, S.y + U.x);   // Wtil[k]
                z[17 * qm + cq]   = make_float2(S.x + U.y, U.x - S.y);   // Wtil[8192-k]
            }
        }
        if (w == 0) {   // self-pair k = 4096 (position 2)
            const float2 Cp = z[2];
            const float2 cA = make_float2(Cp.x, 0.0f);
            const float2 cB = make_float2(Cp.y, 0.0f);
            const float2 Wk = make_float2(0.0f, -1.0f);
            const float2 T  = cmul(Wk, cB);
            const float2 X1 = cadd(cA, T);
            const float2 X2 = make_float2(cA.x - T.x, -(cA.y - T.y));
            const float2 Hp = hrow[(2 << 9)];
            const float2 Y1 = cmul(X1, Hp);
            const float2 Y2 = cmul(X2, Hp);
            const float2 S  = make_float2(Y1.x + Y2.x, Y1.y - Y2.y);
            const float2 Dd = make_float2(Y1.x - Y2.x, Y1.y + Y2.y);
            const float2 Vk = make_float2(0.0f, 1.0f);
            const float2 U  = cmul(Vk, Dd);
            z[2] = make_float2(S.x - U.y, S.y + U.x);
        }
    }
    __syncthreads();
    // ---- inverse radix-4 (m=1)
    {
        const int base = 17 * w;
#pragma unroll
        for (int t = 0; t < 16; ++t) a[t] = z[base + t];
        inv4x4(a);
#pragma unroll
        for (int t = 0; t < 16; ++t) z[base + t] = a[t];
    }
    __syncthreads();
    // ---- P5: inverse radix-16, m2 = 4
    {
        const int j = w & 3, g = w >> 2;
        const int i0 = g * 64 + j;
#pragma unroll
        for (int t = 0; t < 16; ++t) a[t] = z[PHYS(i0 + 4 * t)];
        dit16(a, (float)j * (1.0f / 64.0f));
#pragma unroll
        for (int t = 0; t < 16; ++t) z[PHYS(i0 + 4 * t)] = a[t];
    }
    __syncthreads();
    // ---- P6: inverse radix-16, m2 = 64
    {
        const int j = w & 63, blk = w >> 6;
        const int base = PHYS(blk * 1024 + j);
#pragma unroll
        for (int t = 0; t < 16; ++t) a[t] = z[base + 68 * t];
        dit16(a, (float)j * (1.0f / 1024.0f));
#pragma unroll
        for (int t = 0; t < 16; ++t) z[base + 68 * t] = a[t];
    }
    __syncthreads();
    // ---- P7: inverse radix-4(m=1024) + inverse radix-2(m=4096), keep n<4096, store y
    {
        const float invN = 1.0f / 16384.0f;
        float2* yr = (float2*)yg + (size_t)(b * DCH + d) * 4096;
#pragma unroll
        for (int g = 0; g < 2; ++g) {
            const int i0 = w + 512 * g;
            const int pb = PHYS(i0);
            float2 q0 = z[pb],            q1 = z[pb + 1088],
                   q2 = z[pb + 2 * 1088], q3 = z[pb + 3 * 1088],
                   q4 = z[pb + 4 * 1088], q5 = z[pb + 5 * 1088],
                   q6 = z[pb + 6 * 1088], q7 = z[pb + 7 * 1088];
            const float2 vA  = wtw((float)i0 * (1.0f / 8192.0f));
            const float2 vB  = cmul(vA, vA);
            const float2 vB2 = cmul(vB, vB);
            const float2 vB3 = cmul(vB2, vB);
            // top block inverse radix-4 (m=1024)
            float2 b1 = cmul(q1, vB), b2 = cmul(q2, vB2), b3 = cmul(q3, vB3);
            float2 t0 = cadd(q0, b2), t1 = csub(q0, b2), t2 = cadd(b1, b3);
            float2 dd = csub(b3, b1);
            float2 t3 = make_float2(dd.y, -dd.x);
            float2 T0 = cadd(t0, t2), T1 = cadd(t1, t3), T2 = csub(t0, t2), T3 = csub(t1, t3);
            // bottom block
            b1 = cmul(q5, vB); b2 = cmul(q6, vB2); b3 = cmul(q7, vB3);
            t0 = cadd(q4, b2); t1 = csub(q4, b2); t2 = cadd(b1, b3);
            dd = csub(b3, b1);
            t3 = make_float2(dd.y, -dd.x);
            float2 B0 = cadd(t0, t2), B1 = cadd(t1, t3), B2 = csub(t0, t2), B3 = csub(t1, t3);
            // inverse radix-2: out[n] = T + e^{+2pi i n/8192} * B, n = i0 + 1024*s (n<4096 only)
            float2 o0 = cadd(T0, cmul(B0, vA));
            float2 o1 = cadd(T1, cmul(B1, cmul(vA, make_float2(R2, R2))));
            float2 o2 = cadd(T2, cmul(B2, make_float2(-vA.y, vA.x)));       // i*vA
            float2 o3 = cadd(T3, cmul(B3, cmul(vA, make_float2(-R2, R2))));
            yr[i0]        = make_float2(o0.x * invN, o0.y * invN);
            yr[i0 + 1024] = make_float2(o1.x * invN, o1.y * invN);
            yr[i0 + 2048] = make_float2(o2.x * invN, o2.y * invN);
            yr[i0 + 3072] = make_float2(o3.x * invN, o3.y * invN);
        }
    }
}

// ===================== fallback: verified round-2 16K-FFT kernel =====================
__device__ __forceinline__ int drev14(int v) {
    int r = 0;
#pragma unroll
    for (int i = 0; i < 7; ++i) { r = (r << 2) | (v & 3); v >>= 2; }
    return r;
}
__device__ __forceinline__ int drev10(int v) {
    int r = 0;
#pragma unroll
    for (int i = 0; i < 5; ++i) { r = (r << 2) | (v & 3); v >>= 2; }
    return r;
}

extern "C" __global__ void __launch_bounds__(NTH2, 4)
fftconv_v2(const float* __restrict__ hg, const float* __restrict__ xg,
           const float* __restrict__ bg, float* __restrict__ yg) {
    extern __shared__ float2 z[];
    const int w = threadIdx.x;
    const int bid = blockIdx.x;
    const int d = bid >> 2, b = bid & 3;
    const float* xr = xg + (size_t)(b * DCH + d) * 8192;
    const float* hr = hg + (size_t)d * 8192;
    float2 a[16];
    float xv[8];
    {
#pragma unroll
        for (int t = 0; t < 8; ++t) {
            xv[t] = xr[w + 1024 * t];
            float hv = hr[w + 1024 * t];
            a[t] = make_float2(xv[t], hv);
        }
        const float r1 = -(float)w * (1.0f / 16384.0f);
#pragma unroll
        for (int ai = 0; ai < 4; ++ai) {
            float2 u0 = a[ai], u1 = a[ai + 4];
            float2 mi3 = make_float2(u1.y, -u1.x);
            float2 w1 = wtw(r1 - 0.0625f * ai);
            float2 w2 = cmul(w1, w1), w3 = cmul(w2, w1);
            a[ai]      = cadd(u0, u1);
            a[ai + 4]  = cmul(cadd(u0, mi3), w1);
            a[ai + 8]  = cmul(csub(u0, u1), w2);
            a[ai + 12] = cmul(csub(u0, mi3), w3);
        }
        float2 v1 = wtw(4.0f * r1);
        float2 v2 = cmul(v1, v1), v3 = cmul(v2, v1);
#pragma unroll
        for (int p = 0; p < 4; ++p) {
            float2 u0 = a[4 * p], u1 = a[4 * p + 1], u2 = a[4 * p + 2], u3 = a[4 * p + 3];
            float2 t0 = cadd(u0, u2), t1 = cadd(u1, u3);
            float2 t2 = csub(u0, u2), t3 = csub(u1, u3);
            float2 mi3 = make_float2(t3.y, -t3.x);
            a[4 * p]     = cadd(t0, t1);
            a[4 * p + 1] = cmul(cadd(t2, mi3), v1);
            a[4 * p + 2] = cmul(csub(t0, t1), v2);
            a[4 * p + 3] = cmul(csub(t2, mi3), v3);
        }
        const int base = PHYS(w);
#pragma unroll
        for (int t = 0; t < 16; ++t) z[base + 1088 * t] = a[t];
    }
    __syncthreads();
    {
        const int j = w & 63, grp = w >> 6;
        const int base = PHYS(grp * 1024 + j);
#pragma unroll
        for (int t = 0; t < 16; ++t) a[t] = z[base + 68 * t];
        dif16(a, -(float)j * (1.0f / 1024.0f));
#pragma unroll
        for (int t = 0; t < 16; ++t) z[base + 68 * t] = a[t];
    }
    __syncthreads();
    {
        const int j = w & 3, grp = w >> 2;
        const int i0 = grp * 64 + j;
#pragma unroll
        for (int t = 0; t < 16; ++t) a[t] = z[PHYS(i0 + 4 * t)];
        dif16(a, -(float)j * (1.0f / 64.0f));
#pragma unroll
        for (int t = 0; t < 16; ++t) z[PHYS(i0 + 4 * t)] = a[t];
    }
    __syncthreads();
    {
        const int base = 17 * w;
#pragma unroll
        for (int t = 0; t < 16; ++t) a[t] = z[base + t];
        fwd4x4(a);
#pragma unroll
        for (int t = 0; t < 16; ++t) z[base + t] = a[t];
        __syncthreads();
        const int kw = drev10(w);
#pragma unroll
        for (int t = 0; t < 16; ++t) {
            const int rt = (((t & 3) << 2) | (t >> 2));
            const int k = (rt << 10) | kw;
            const int pp = drev14(16384 - k);
            const float2 Zm = z[PHYS(pp)];
            const float2 Zp = a[t];
            const float2 A  = make_float2(Zp.x + Zm.x, Zp.y - Zm.y);
            const float2 Dv = make_float2(Zp.x - Zm.x, Zp.y + Zm.y);
            const float2 X  = make_float2(0.5f * A.x, 0.5f * A.y);
            const float2 H  = make_float2(0.5f * Dv.y, -0.5f * Dv.x);
            a[t] = cmul(X, H);
        }
        __syncthreads();
        inv4x4(a);
#pragma unroll
        for (int t = 0; t < 16; ++t) z[base + t] = a[t];
    }
    __syncthreads();
    {
        const int j = w & 3, grp = w >> 2;
        const int i0 = grp * 64 + j;
#pragma unroll
        for (int t = 0; t < 16; ++t) a[t] = z[PHYS(i0 + 4 * t)];
        dit16(a, (float)j * (1.0f / 64.0f));
#pragma unroll
        for (int t = 0; t < 16; ++t) z[PHYS(i0 + 4 * t)] = a[t];
    }
    __syncthreads();
    {
        const int j = w & 63, grp = w >> 6;
        const int base = PHYS(grp * 1024 + j);
#pragma unroll
        for (int t = 0; t < 16; ++t) a[t] = z[base + 68 * t];
        dit16(a, (float)j * (1.0f / 1024.0f));
#pragma unroll
        for (int t = 0; t < 16; ++t) z[base + 68 * t] = a[t];
    }
    __syncthreads();
    {
        const int base = PHYS(w);
#pragma unroll
        for (int t = 0; t < 16; ++t) a[t] = z[base + 1088 * t];
        const float r1 = (float)w * (1.0f / 16384.0f);
        float2 v1 = wtw(4.0f * r1);
        float2 v2 = cmul(v1, v1), v3 = cmul(v2, v1);
#pragma unroll
        for (int p = 0; p < 4; ++p) {
            float2 b0 = a[4 * p];
            float2 b1 = cmul(a[4 * p + 1], v1);
            float2 b2 = cmul(a[4 * p + 2], v2);
            float2 b3 = cmul(a[4 * p + 3], v3);
            float2 t0 = cadd(b0, b2), t1 = csub(b0, b2);
            float2 t2 = cadd(b1, b3);
            float2 dd = csub(b3, b1);
            float2 t3 = make_float2(dd.y, -dd.x);
            a[4 * p]     = cadd(t0, t2);
            a[4 * p + 1] = cadd(t1, t3);
            a[4 * p + 2] = csub(t0, t2);
            a[4 * p + 3] = csub(t1, t3);
        }
        const float bd = bg[d];
        const float invN = 1.0f / 16384.0f;
#pragma unroll
        for (int ai = 0; ai < 4; ++ai) {
            float2 w1 = wtw(r1 + 0.0625f * ai);
            float2 w2 = cmul(w1, w1), w3 = cmul(w2, w1);
            float2 b0 = a[ai];
            float2 vv1 = cmul(a[ai + 4], w1);
            float2 vv2 = cmul(a[ai + 8], w2);
            float2 vv3 = cmul(a[ai + 12], w3);
            float2 t0 = cadd(b0, vv2), t1 = csub(b0, vv2);
            float2 t2 = cadd(vv1, vv3);
            float2 dd = csub(vv3, vv1);
            float2 t3 = make_float2(dd.y, -dd.x);
            float2 o0 = cadd(t0, t2);
            float2 o1 = cadd(t1, t3);
            yg[(size_t)(b * DCH + d) * 8192 + w + 1024 * ai]        = fmaf(xv[ai], bd, o0.x * invN);
            yg[(size_t)(b * DCH + d) * 8192 + w + 4096 + 1024 * ai] = fmaf(xv[ai + 4], bd, o1.x * invN);
        }
    }
}

extern "C" void kernel_launch(void* const* d_in, const int* in_sizes, int n_in,
                              void* d_out, int out_size, void* d_ws, size_t ws_size,
                              hipStream_t stream) {
    (void)in_sizes; (void)n_in; (void)out_size;
    const float* h = (const float*)d_in[0];
    const float* x = (const float*)d_in[1];
    const float* B = (const float*)d_in[2];
    float* y = (float*)d_out;

    const size_t need = (size_t)(DCH * NHALF + DCH) * sizeof(float2);
    if (ws_size >= need && d_ws != nullptr) {
        (void)hipFuncSetAttribute((const void*)hspec_kernel,
                                  hipFuncAttributeMaxDynamicSharedMemorySize,
                                  LDSE * (int)sizeof(float2));
        (void)hipFuncSetAttribute((const void*)fftconv_main,
                                  hipFuncAttributeMaxDynamicSharedMemorySize,
                                  LDSE * (int)sizeof(float2));
        float* wsHf = (float*)d_ws;
        float* wsNy = wsHf + 2 * (size_t)DCH * NHALF;
        hspec_kernel<<<dim3(DCH), dim3(NTH), LDSE * sizeof(float2), stream>>>(h, B, wsHf, wsNy);
        fftconv_main<<<dim3(4 * DCH), dim3(NTH), LDSE * sizeof(float2), stream>>>(x, wsHf, wsNy, y);
    } else {
        (void)hipFuncSetAttribute((const void*)fftconv_v2,
                                  hipFuncAttributeMaxDynamicSharedMemorySize,
                                  LDSE2 * (int)sizeof(float2));
        fftconv_v2<<<dim3(4 * DCH), dim3(NTH2), LDSE2 * sizeof(float2), stream>>>(h, x, B, y);
    }
}

// Round 4
// 139.855 us; speedup vs baseline: 3.7202x; 1.0066x over previous
//
#include <hip/hip_runtime.h>

#define DCH   768
#define NHALF 8192
#define NTH   512
#define PHYS(i) ((i) + ((i) >> 4))
#define LDSE  (NHALF + NHALF / 16)     // 8704 float2 = 69632 B
#define NFULL 16384
#define NTH2  1024
#define LDSE2 (NFULL + NFULL / 16)     // 17408 float2 = 139264 B

#define C1F 0.9238795325112867f        // cos(pi/8)
#define S1F 0.3826834323650898f        // sin(pi/8)
#define C2F 0.7071067811865476f        // cos(pi/4)

__device__ __forceinline__ float2 cmul(float2 a, float2 b) {
    return make_float2(fmaf(a.x, b.x, -(a.y * b.y)), fmaf(a.x, b.y, a.y * b.x));
}
__device__ __forceinline__ float2 cadd(float2 a, float2 b) { return make_float2(a.x + b.x, a.y + b.y); }
__device__ __forceinline__ float2 csub(float2 a, float2 b) { return make_float2(a.x - b.x, a.y - b.y); }
__device__ __forceinline__ float2 wtw(float rev) {   // e^{2*pi*i*rev}
    return make_float2(__builtin_amdgcn_cosf(rev), __builtin_amdgcn_sinf(rev));
}
__device__ __forceinline__ int drev8(int v) {        // 4-digit base-4 reversal of 8-bit
    return ((v & 3) << 6) | ((v & 12) << 2) | ((v >> 2) & 12) | ((v >> 6) & 3);
}
__device__ __forceinline__ constexpr int rev2i(int a) { return ((a & 3) << 2) | ((a >> 2) & 3); }
__device__ __forceinline__ constexpr int rtof(int t)  { return ((t & 3) << 2) | (t >> 2); }

__device__ __forceinline__ float2 Ktw(int rt) {      // e^{-2*pi*i*rt/32}
    const float KC[16] = {1.0f, 0.980785280f, 0.923879533f, 0.831469612f,
                          0.707106781f, 0.555570233f, 0.382683432f, 0.195090322f,
                          0.0f, -0.195090322f, -0.382683432f, -0.555570233f,
                          -0.707106781f, -0.831469612f, -0.923879533f, -0.980785280f};
    const float KS[16] = {0.0f, -0.195090322f, -0.382683432f, -0.555570233f,
                          -0.707106781f, -0.831469612f, -0.923879533f, -0.980785280f,
                          -1.0f, -0.980785280f, -0.923879533f, -0.831469612f,
                          -0.707106781f, -0.555570233f, -0.382683432f, -0.195090322f};
    return make_float2(KC[rt], KS[rt]);
}

// -------- fused radix-16 DIF (levels m1=4*m2 then m2); r1 = -j/(16*m2)
// 1 sincos total; per-ai twiddles via constant rotations e^{-2pi i*ai/16}.
__device__ __forceinline__ void dif16(float2* a, float r1) {
    const float2 w10 = wtw(r1);
    const float2 sq  = cmul(w10, w10);
    const float2 cu  = cmul(sq, w10);
#pragma unroll
    for (int ai = 0; ai < 4; ++ai) {
        float2 w1, w2, w3;
        if (ai == 0)      { w1 = w10; w2 = sq; w3 = cu; }
        else if (ai == 1) { w1 = cmul(w10, make_float2(C1F, -S1F));
                            w2 = cmul(sq,  make_float2(C2F, -C2F));
                            w3 = cmul(cu,  make_float2(S1F, -C1F)); }
        else if (ai == 2) { w1 = cmul(w10, make_float2(C2F, -C2F));
                            w2 = make_float2(sq.y, -sq.x);           // sq * (-i)
                            w3 = cmul(cu,  make_float2(-C2F, -C2F)); }
        else              { w1 = cmul(w10, make_float2(S1F, -C1F));
                            w2 = cmul(sq,  make_float2(-C2F, -C2F));
                            w3 = cmul(cu,  make_float2(-C1F,  S1F)); }
        float2 u0 = a[ai], u1 = a[ai + 4], u2 = a[ai + 8], u3 = a[ai + 12];
        float2 t0 = cadd(u0, u2), t1 = cadd(u1, u3);
        float2 t2 = csub(u0, u2), t3 = csub(u1, u3);
        float2 mi3 = make_float2(t3.y, -t3.x);
        a[ai]      = cadd(t0, t1);
        a[ai + 4]  = cmul(cadd(t2, mi3), w1);
        a[ai + 8]  = cmul(csub(t0, t1), w2);
        a[ai + 12] = cmul(csub(t2, mi3), w3);
    }
    const float2 v1 = cmul(sq, sq);                  // w10^4 = e^{2pi i*4*r1}
    const float2 v2 = cmul(v1, v1);
    const float2 v3 = cmul(v2, v1);
#pragma unroll
    for (int p = 0; p < 4; ++p) {
        float2 u0 = a[4 * p], u1 = a[4 * p + 1], u2 = a[4 * p + 2], u3 = a[4 * p + 3];
        float2 t0 = cadd(u0, u2), t1 = cadd(u1, u3);
        float2 t2 = csub(u0, u2), t3 = csub(u1, u3);
        float2 mi3 = make_float2(t3.y, -t3.x);
        a[4 * p]     = cadd(t0, t1);
        a[4 * p + 1] = cmul(cadd(t2, mi3), v1);
        a[4 * p + 2] = cmul(csub(t0, t1), v2);
        a[4 * p + 3] = cmul(csub(t2, mi3), v3);
    }
}
// -------- fused inverse radix-16 (levels m2 then m1=4*m2); r1 = +j/(16*m2)
__device__ __forceinline__ void dit16(float2* a, float r1) {
    const float2 w10 = wtw(r1);
    const float2 sq  = cmul(w10, w10);
    const float2 cu  = cmul(sq, w10);
    const float2 v1  = cmul(sq, sq);
    const float2 v2  = cmul(v1, v1);
    const float2 v3  = cmul(v2, v1);
#pragma unroll
    for (int p = 0; p < 4; ++p) {
        float2 b0 = a[4 * p];
        float2 b1 = cmul(a[4 * p + 1], v1);
        float2 b2 = cmul(a[4 * p + 2], v2);
        float2 b3 = cmul(a[4 * p + 3], v3);
        float2 t0 = cadd(b0, b2), t1 = csub(b0, b2);
        float2 t2 = cadd(b1, b3);
        float2 dd = csub(b3, b1);
        float2 t3 = make_float2(dd.y, -dd.x);
        a[4 * p]     = cadd(t0, t2);
        a[4 * p + 1] = cadd(t1, t3);
        a[4 * p + 2] = csub(t0, t2);
        a[4 * p + 3] = csub(t1, t3);
    }
#pragma unroll
    for (int ai = 0; ai < 4; ++ai) {
        float2 w1, w2, w3;
        if (ai == 0)      { w1 = w10; w2 = sq; w3 = cu; }
        else if (ai == 1) { w1 = cmul(w10, make_float2(C1F, S1F));
                            w2 = cmul(sq,  make_float2(C2F, C2F));
                            w3 = cmul(cu,  make_float2(S1F, C1F)); }
        else if (ai == 2) { w1 = cmul(w10, make_float2(C2F, C2F));
                            w2 = make_float2(-sq.y, sq.x);           // sq * (+i)
                            w3 = cmul(cu,  make_float2(-C2F, C2F)); }
        else              { w1 = cmul(w10, make_float2(S1F, C1F));
                            w2 = cmul(sq,  make_float2(-C2F, C2F));
                            w3 = cmul(cu,  make_float2(-C1F, -S1F)); }
        float2 b0 = a[ai];
        float2 b1 = cmul(a[ai + 4], w1);
        float2 b2 = cmul(a[ai + 8], w2);
        float2 b3 = cmul(a[ai + 12], w3);
        float2 t0 = cadd(b0, b2), t1 = csub(b0, b2);
        float2 t2 = cadd(b1, b3);
        float2 dd = csub(b3, b1);
        float2 t3 = make_float2(dd.y, -dd.x);
        a[ai]      = cadd(t0, t2);
        a[ai + 4]  = cadd(t1, t3);
        a[ai + 8]  = csub(t0, t2);
        a[ai + 12] = csub(t1, t3);
    }
}
__device__ __forceinline__ void fwd4x4(float2* a) {   // radix-4 DIF, m=1, twiddle-free
#pragma unroll
    for (int u = 0; u < 4; ++u) {
        float2 u0 = a[4*u], u1 = a[4*u+1], u2 = a[4*u+2], u3 = a[4*u+3];
        float2 t0 = cadd(u0, u2), t1 = cadd(u1, u3), t2 = csub(u0, u2), t3 = csub(u1, u3);
        float2 mi3 = make_float2(t3.y, -t3.x);
        a[4*u] = cadd(t0, t1); a[4*u+1] = cadd(t2, mi3);
        a[4*u+2] = csub(t0, t1); a[4*u+3] = csub(t2, mi3);
    }
}
__device__ __forceinline__ void inv4x4(float2* a) {   // inverse radix-4, m=1
#pragma unroll
    for (int u = 0; u < 4; ++u) {
        float2 b0 = a[4*u], b1 = a[4*u+1], b2 = a[4*u+2], b3 = a[4*u+3];
        float2 t0 = cadd(b0, b2), t1 = csub(b0, b2), t2 = cadd(b1, b3);
        float2 dd = csub(b3, b1);
        float2 t3 = make_float2(dd.y, -dd.x);
        a[4*u] = cadd(t0, t2); a[4*u+1] = cadd(t1, t3);
        a[4*u+2] = csub(t0, t2); a[4*u+3] = csub(t1, t3);
    }
}

// Forward 8192-pt complex FFT of src (4096 nonzero float2, top half zero).
// On return: z holds C in scrambled order, a[16] holds thread's own 16 values.
__device__ __forceinline__ void fwd8k(const float2* __restrict__ src,
                                      float2* __restrict__ z, const int w, float2* a) {
    const float R2 = 0.70710678118654752f;
    // ---- P1: radix-2(m=4096, top half zero) + radix-4(m=1024) from global
#pragma unroll
    for (int g = 0; g < 2; ++g) {
        const int i0 = w + 512 * g;
        float2 c0 = src[i0], c1 = src[i0 + 1024], c2 = src[i0 + 2048], c3 = src[i0 + 3072];
        const float2 wA  = wtw(-(float)i0 * (1.0f / 8192.0f));
        const float2 wB  = cmul(wA, wA);
        const float2 wB2 = cmul(wB, wB);
        const float2 wB3 = cmul(wB2, wB);
        const int pb = PHYS(i0);
        float2 t0 = cadd(c0, c2), t1 = cadd(c1, c3), t2 = csub(c0, c2), t3 = csub(c1, c3);
        float2 mi3 = make_float2(t3.y, -t3.x);
        z[pb]            = cadd(t0, t1);
        z[pb + 1088]     = cmul(cadd(t2, mi3), wB);
        z[pb + 2 * 1088] = cmul(csub(t0, t1), wB2);
        z[pb + 3 * 1088] = cmul(csub(t2, mi3), wB3);
        float2 d0 = cmul(c0, wA);
        float2 d1 = cmul(c1, cmul(wA, make_float2(R2, -R2)));
        float2 d2 = cmul(c2, make_float2(wA.y, -wA.x));           // -i*wA
        float2 d3 = cmul(c3, cmul(wA, make_float2(-R2, -R2)));
        t0 = cadd(d0, d2); t1 = cadd(d1, d3); t2 = csub(d0, d2); t3 = csub(d1, d3);
        mi3 = make_float2(t3.y, -t3.x);
        z[pb + 4 * 1088] = cadd(t0, t1);
        z[pb + 5 * 1088] = cmul(cadd(t2, mi3), wB);
        z[pb + 6 * 1088] = cmul(csub(t0, t1), wB2);
        z[pb + 7 * 1088] = cmul(csub(t2, mi3), wB3);
    }
    __syncthreads();
    // ---- P2: radix-16, m2 = 64
    {
        const int j = w & 63, blk = w >> 6;
        const int base = PHYS(blk * 1024 + j);
#pragma unroll
        for (int t = 0; t < 16; ++t) a[t] = z[base + 68 * t];
        dif16(a, -(float)j * (1.0f / 1024.0f));
#pragma unroll
        for (int t = 0; t < 16; ++t) z[base + 68 * t] = a[t];
    }
    __syncthreads();
    // ---- P3: radix-16, m2 = 4
    {
        const int j = w & 3, g = w >> 2;
        const int i0 = g * 64 + j;
#pragma unroll
        for (int t = 0; t < 16; ++t) a[t] = z[PHYS(i0 + 4 * t)];
        dif16(a, -(float)j * (1.0f / 64.0f));
#pragma unroll
        for (int t = 0; t < 16; ++t) z[PHYS(i0 + 4 * t)] = a[t];
    }
    __syncthreads();
    // ---- P4a: final radix-4 (m=1) in regs, publish C
    {
        const int base = 17 * w;
#pragma unroll
        for (int t = 0; t < 16; ++t) a[t] = z[base + t];
        fwd4x4(a);
#pragma unroll
        for (int t = 0; t < 16; ++t) z[base + t] = a[t];
    }
    __syncthreads();
}

// ============ kernel 1: per-channel H spectrum, scaled by 1/N, H += B
extern "C" __global__ void __launch_bounds__(NTH, 4)
hspec_kernel(const float* __restrict__ hg, const float* __restrict__ bg,
             float* __restrict__ wsHf, float* __restrict__ wsNy) {
    extern __shared__ float2 z[];
    const int w = threadIdx.x;
    const int d = blockIdx.x;
    const float2* hr = (const float2*)hg + (size_t)d * 4096;
    float2 a[16];
    fwd8k(hr, z, w, a);

    const float Bd = bg[d];
    const float invN = 1.0f / 16384.0f;
    float2* out = (float2*)wsHf + (size_t)d * NHALF;
    const int wm = w & 255, whi = w >> 8;
    const int k0 = 2 * drev8(wm) + whi;
    const float2 wk0 = wtw(-(float)k0 * (1.0f / 16384.0f));
    int qm = 0;
    if (w != 0) { const int bq = (512 - k0) >> 1; qm = (whi << 8) | drev8(bq); }
#pragma unroll
    for (int t = 0; t < 16; ++t) {
        const int rt = rtof(t);
        if (w == 0 && t == 0) {
            float2 C0 = a[0];
            out[0] = make_float2((C0.x + C0.y + Bd) * invN, 0.0f);
            ((float2*)wsNy)[d] = make_float2((C0.x - C0.y + Bd) * invN, 0.0f);
        } else {
            const int cq = (w == 0) ? rev2i(16 - rt) : rev2i(15 - rt);
            const float2 Cq = z[17 * qm + cq];
            const float2 Cp = a[t];
            const float2 cA = make_float2(0.5f * (Cp.x + Cq.x), 0.5f * (Cp.y - Cq.y));
            const float2 cB = make_float2(0.5f * (Cp.y + Cq.y), -0.5f * (Cp.x - Cq.x));
            const float2 Wk = cmul(wk0, Ktw(rt));
            const float2 Hf = cadd(cA, cmul(Wk, cB));
            out[(t << 9) + w] = make_float2((Hf.x + Bd) * invN, Hf.y * invN);
        }
    }
}

// ============ kernel 2: main conv
extern "C" __global__ void __launch_bounds__(NTH, 4)
fftconv_main(const float* __restrict__ xg, const float* __restrict__ wsHf,
             const float* __restrict__ wsNy, float* __restrict__ yg) {
    extern __shared__ float2 z[];
    const int w = threadIdx.x;
    const int bid = blockIdx.x;
    const int d = bid >> 2, b = bid & 3;
    const float2* xr = (const float2*)xg + (size_t)(b * DCH + d) * 4096;
    const float2* hrow = (const float2*)wsHf + (size_t)d * NHALF;
    const float R2 = 0.70710678118654752f;
    float2 a[16];
    fwd8k(xr, z, w, a);

    // ---- P4b: pair-owner combine. Owner results stay in a[t]; only partner
    // slots (non-owner positions, written by exactly their pair's owner) hit LDS.
    {
        const int wm = w & 255, whi = w >> 8;
        const int k0 = 2 * drev8(wm) + whi;
        const float2 wk0 = wtw(-(float)k0 * (1.0f / 16384.0f));
        int qm = 0;
        if (w != 0) { const int bq = (512 - k0) >> 1; qm = (whi << 8) | drev8(bq); }
#pragma unroll
        for (int t = 0; t < 16; ++t) {
            if ((t & 3) > 1) continue;           // owner elements: rt < 8
            const int rt = rtof(t);
            if (w == 0 && t == 0) {
                float2 C0 = a[0];
                float X0 = C0.x + C0.y, XN = C0.x - C0.y;
                float2 H0 = hrow[0];
                float2 HN = ((const float2*)wsNy)[d];
                float2 Y1 = make_float2(X0 * H0.x, X0 * H0.y);
                float2 Y2 = make_float2(XN * HN.x, XN * HN.y);
                float2 S  = make_float2(Y1.x + Y2.x, Y1.y - Y2.y);
                float2 Dd = make_float2(Y1.x - Y2.x, Y1.y + Y2.y);
                a[0] = make_float2(S.x - Dd.y, S.y + Dd.x);      // keep in regs
            } else {
                const int cq = (w == 0) ? rev2i(16 - rt) : rev2i(15 - rt);
                const float2 Cq = z[17 * qm + cq];
                const float2 Cp = a[t];
                const float2 cA = make_float2(0.5f * (Cp.x + Cq.x), 0.5f * (Cp.y - Cq.y));
                const float2 cB = make_float2(0.5f * (Cp.y + Cq.y), -0.5f * (Cp.x - Cq.x));
                const float2 Wk = cmul(wk0, Ktw(rt));
                const float2 T  = cmul(Wk, cB);
                const float2 X1 = cadd(cA, T);
                const float2 X2 = make_float2(cA.x - T.x, -(cA.y - T.y));  // conj(cA - T)
                const float2 Hp = hrow[(t << 9) + w];
                const float2 Hq = hrow[(cq << 9) + qm];
                const float2 Y1 = cmul(X1, Hp);
                const float2 Y2 = cmul(X2, Hq);
                const float2 S  = make_float2(Y1.x + Y2.x, Y1.y - Y2.y);
                const float2 Dd = make_float2(Y1.x - Y2.x, Y1.y + Y2.y);
                const float2 Vk = make_float2(Wk.x, -Wk.y);
                const float2 U  = cmul(Vk, Dd);
                a[t]            = make_float2(S.x - U.y, S.y + U.x);     // own Wtil[k]
                z[17 * qm + cq] = make_float2(S.x + U.y, U.x - S.y);     // partner Wtil
            }
        }
        if (w == 0) {   // self-pair k = 4096 (position 2, non-owner slot of thread 0)
            const float2 Cp = z[2];
            const float2 cA = make_float2(Cp.x, 0.0f);
            const float2 cB = make_float2(Cp.y, 0.0f);
            const float2 Wk = make_float2(0.0f, -1.0f);
            const float2 T  = cmul(Wk, cB);
            const float2 X1 = cadd(cA, T);
            const float2 X2 = make_float2(cA.x - T.x, -(cA.y - T.y));
            const float2 Hp = hrow[(2 << 9)];
            const float2 Y1 = cmul(X1, Hp);
            const float2 Y2 = cmul(X2, Hp);
            const float2 S  = make_float2(Y1.x + Y2.x, Y1.y - Y2.y);
            const float2 Dd = make_float2(Y1.x - Y2.x, Y1.y + Y2.y);
            const float2 Vk = make_float2(0.0f, 1.0f);
            const float2 U  = cmul(Vk, Dd);
            z[2] = make_float2(S.x - U.y, S.y + U.x);
        }
    }
    __syncthreads();
    // ---- inverse radix-4 (m=1): own 8 from regs, missing 8 from LDS
    {
        const int base = 17 * w;
#pragma unroll
        for (int t = 0; t < 16; ++t)
            if ((t & 3) > 1) a[t] = z[base + t];
        inv4x4(a);
#pragma unroll
        for (int t = 0; t < 16; ++t) z[base + t] = a[t];
    }
    __syncthreads();
    // ---- P5: inverse radix-16, m2 = 4
    {
        const int j = w & 3, g = w >> 2;
        const int i0 = g * 64 + j;
#pragma unroll
        for (int t = 0; t < 16; ++t) a[t] = z[PHYS(i0 + 4 * t)];
        dit16(a, (float)j * (1.0f / 64.0f));
#pragma unroll
        for (int t = 0; t < 16; ++t) z[PHYS(i0 + 4 * t)] = a[t];
    }
    __syncthreads();
    // ---- P6: inverse radix-16, m2 = 64
    {
        const int j = w & 63, blk = w >> 6;
        const int base = PHYS(blk * 1024 + j);
#pragma unroll
        for (int t = 0; t < 16; ++t) a[t] = z[base + 68 * t];
        dit16(a, (float)j * (1.0f / 1024.0f));
#pragma unroll
        for (int t = 0; t < 16; ++t) z[base + 68 * t] = a[t];
    }
    __syncthreads();
    // ---- P7: inverse radix-4(m=1024) + inverse radix-2(m=4096), keep n<4096, store y
    {
        float2* yr = (float2*)yg + (size_t)(b * DCH + d) * 4096;
#pragma unroll
        for (int g = 0; g < 2; ++g) {
            const int i0 = w + 512 * g;
            const int pb = PHYS(i0);
            float2 q0 = z[pb],            q1 = z[pb + 1088],
                   q2 = z[pb + 2 * 1088], q3 = z[pb + 3 * 1088],
                   q4 = z[pb + 4 * 1088], q5 = z[pb + 5 * 1088],
                   q6 = z[pb + 6 * 1088], q7 = z[pb + 7 * 1088];
            const float2 vA  = wtw((float)i0 * (1.0f / 8192.0f));
            const float2 vB  = cmul(vA, vA);
            const float2 vB2 = cmul(vB, vB);
            const float2 vB3 = cmul(vB2, vB);
            float2 b1 = cmul(q1, vB), b2 = cmul(q2, vB2), b3 = cmul(q3, vB3);
            float2 t0 = cadd(q0, b2), t1 = csub(q0, b2), t2 = cadd(b1, b3);
            float2 dd = csub(b3, b1);
            float2 t3 = make_float2(dd.y, -dd.x);
            float2 T0 = cadd(t0, t2), T1 = cadd(t1, t3), T2 = csub(t0, t2), T3 = csub(t1, t3);
            b1 = cmul(q5, vB); b2 = cmul(q6, vB2); b3 = cmul(q7, vB3);
            t0 = cadd(q4, b2); t1 = csub(q4, b2); t2 = cadd(b1, b3);
            dd = csub(b3, b1);
            t3 = make_float2(dd.y, -dd.x);
            float2 B0 = cadd(t0, t2), B1 = cadd(t1, t3), B2 = csub(t0, t2), B3 = csub(t1, t3);
            // 1/N already folded into H-spectrum
            yr[i0]        = cadd(T0, cmul(B0, vA));
            yr[i0 + 1024] = cadd(T1, cmul(B1, cmul(vA, make_float2(R2, R2))));
            yr[i0 + 2048] = cadd(T2, cmul(B2, make_float2(-vA.y, vA.x)));   // i*vA
            yr[i0 + 3072] = cadd(T3, cmul(B3, cmul(vA, make_float2(-R2, R2))));
        }
    }
}

// ===================== fallback: verified 16K-FFT single-kernel path =====================
__device__ __forceinline__ int drev14(int v) {
    int r = 0;
#pragma unroll
    for (int i = 0; i < 7; ++i) { r = (r << 2) | (v & 3); v >>= 2; }
    return r;
}
__device__ __forceinline__ int drev10(int v) {
    int r = 0;
#pragma unroll
    for (int i = 0; i < 5; ++i) { r = (r << 2) | (v & 3); v >>= 2; }
    return r;
}

extern "C" __global__ void __launch_bounds__(NTH2, 4)
fftconv_v2(const float* __restrict__ hg, const float* __restrict__ xg,
           const float* __restrict__ bg, float* __restrict__ yg) {
    extern __shared__ float2 z[];
    const int w = threadIdx.x;
    const int bid = blockIdx.x;
    const int d = bid >> 2, b = bid & 3;
    const float* xr = xg + (size_t)(b * DCH + d) * 8192;
    const float* hr = hg + (size_t)d * 8192;
    float2 a[16];
    float xv[8];
    {
#pragma unroll
        for (int t = 0; t < 8; ++t) {
            xv[t] = xr[w + 1024 * t];
            float hv = hr[w + 1024 * t];
            a[t] = make_float2(xv[t], hv);
        }
        const float r1 = -(float)w * (1.0f / 16384.0f);
#pragma unroll
        for (int ai = 0; ai < 4; ++ai) {
            float2 u0 = a[ai], u1 = a[ai + 4];
            float2 mi3 = make_float2(u1.y, -u1.x);
            float2 w1 = wtw(r1 - 0.0625f * ai);
            float2 w2 = cmul(w1, w1), w3 = cmul(w2, w1);
            a[ai]      = cadd(u0, u1);
            a[ai + 4]  = cmul(cadd(u0, mi3), w1);
            a[ai + 8]  = cmul(csub(u0, u1), w2);
            a[ai + 12] = cmul(csub(u0, mi3), w3);
        }
        float2 v1 = wtw(4.0f * r1);
        float2 v2 = cmul(v1, v1), v3 = cmul(v2, v1);
#pragma unroll
        for (int p = 0; p < 4; ++p) {
            float2 u0 = a[4 * p], u1 = a[4 * p + 1], u2 = a[4 * p + 2], u3 = a[4 * p + 3];
            float2 t0 = cadd(u0, u2), t1 = cadd(u1, u3);
            float2 t2 = csub(u0, u2), t3 = csub(u1, u3);
            float2 mi3 = make_float2(t3.y, -t3.x);
            a[4 * p]     = cadd(t0, t1);
            a[4 * p + 1] = cmul(cadd(t2, mi3), v1);
            a[4 * p + 2] = cmul(csub(t0, t1), v2);
            a[4 * p + 3] = cmul(csub(t2, mi3), v3);
        }
        const int base = PHYS(w);
#pragma unroll
        for (int t = 0; t < 16; ++t) z[base + 1088 * t] = a[t];
    }
    __syncthreads();
    {
        const int j = w & 63, grp = w >> 6;
        const int base = PHYS(grp * 1024 + j);
#pragma unroll
        for (int t = 0; t < 16; ++t) a[t] = z[base + 68 * t];
        dif16(a, -(float)j * (1.0f / 1024.0f));
#pragma unroll
        for (int t = 0; t < 16; ++t) z[base + 68 * t] = a[t];
    }
    __syncthreads();
    {
        const int j = w & 3, grp = w >> 2;
        const int i0 = grp * 64 + j;
#pragma unroll
        for (int t = 0; t < 16; ++t) a[t] = z[PHYS(i0 + 4 * t)];
        dif16(a, -(float)j * (1.0f / 64.0f));
#pragma unroll
        for (int t = 0; t < 16; ++t) z[PHYS(i0 + 4 * t)] = a[t];
    }
    __syncthreads();
    {
        const int base = 17 * w;
#pragma unroll
        for (int t = 0; t < 16; ++t) a[t] = z[base + t];
        fwd4x4(a);
#pragma unroll
        for (int t = 0; t < 16; ++t) z[base + t] = a[t];
        __syncthreads();
        const int kw = drev10(w);
#pragma unroll
        for (int t = 0; t < 16; ++t) {
            const int rt = (((t & 3) << 2) | (t >> 2));
            const int k = (rt << 10) | kw;
            const int pp = drev14(16384 - k);
            const float2 Zm = z[PHYS(pp)];
            const float2 Zp = a[t];
            const float2 A  = make_float2(Zp.x + Zm.x, Zp.y - Zm.y);
            const float2 Dv = make_float2(Zp.x - Zm.x, Zp.y + Zm.y);
            const float2 X  = make_float2(0.5f * A.x, 0.5f * A.y);
            const float2 H  = make_float2(0.5f * Dv.y, -0.5f * Dv.x);
            a[t] = cmul(X, H);
        }
        __syncthreads();
        inv4x4(a);
#pragma unroll
        for (int t = 0; t < 16; ++t) z[base + t] = a[t];
    }
    __syncthreads();
    {
        const int j = w & 3, grp = w >> 2;
        const int i0 = grp * 64 + j;
#pragma unroll
        for (int t = 0; t < 16; ++t) a[t] = z[PHYS(i0 + 4 * t)];
        dit16(a, (float)j * (1.0f / 64.0f));
#pragma unroll
        for (int t = 0; t < 16; ++t) z[PHYS(i0 + 4 * t)] = a[t];
    }
    __syncthreads();
    {
        const int j = w & 63, grp = w >> 6;
        const int base = PHYS(grp * 1024 + j);
#pragma unroll
        for (int t = 0; t < 16; ++t) a[t] = z[base + 68 * t];
        dit16(a, (float)j * (1.0f / 1024.0f));
#pragma unroll
        for (int t = 0; t < 16; ++t) z[base + 68 * t] = a[t];
    }
    __syncthreads();
    {
        const int base = PHYS(w);
#pragma unroll
        for (int t = 0; t < 16; ++t) a[t] = z[base + 1088 * t];
        const float r1 = (float)w * (1.0f / 16384.0f);
        float2 v1 = wtw(4.0f * r1);
        float2 v2 = cmul(v1, v1), v3 = cmul(v2, v1);
#pragma unroll
        for (int p = 0; p < 4; ++p) {
            float2 b0 = a[4 * p];
            float2 b1 = cmul(a[4 * p + 1], v1);
            float2 b2 = cmul(a[4 * p + 2], v2);
            float2 b3 = cmul(a[4 * p + 3], v3);
            float2 t0 = cadd(b0, b2), t1 = csub(b0, b2);
            float2 t2 = cadd(b1, b3);
            float2 dd = csub(b3, b1);
            float2 t3 = make_float2(dd.y, -dd.x);
            a[4 * p]     = cadd(t0, t2);
            a[4 * p + 1] = cadd(t1, t3);
            a[4 * p + 2] = csub(t0, t2);
            a[4 * p + 3] = csub(t1, t3);
        }
        const float bd = bg[d];
        const float invN = 1.0f / 16384.0f;
#pragma unroll
        for (int ai = 0; ai < 4; ++ai) {
            float2 w1 = wtw(r1 + 0.0625f * ai);
            float2 w2 = cmul(w1, w1), w3 = cmul(w2, w1);
            float2 b0 = a[ai];
            float2 vv1 = cmul(a[ai + 4], w1);
            float2 vv2 = cmul(a[ai + 8], w2);
            float2 vv3 = cmul(a[ai + 12], w3);
            float2 t0 = cadd(b0, vv2), t1 = csub(b0, vv2);
            float2 t2 = cadd(vv1, vv3);
            float2 dd = csub(vv3, vv1);
            float2 t3 = make_float2(dd.y, -dd.x);
            float2 o0 = cadd(t0, t2);
            float2 o1 = cadd(t1, t3);
            yg[(size_t)(b * DCH + d) * 8192 + w + 1024 * ai]        = fmaf(xv[ai], bd, o0.x * invN);
            yg[(size_t)(b * DCH + d) * 8192 + w + 4096 + 1024 * ai] = fmaf(xv[ai + 4], bd, o1.x * invN);
        }
    }
}

extern "C" void kernel_launch(void* const* d_in, const int* in_sizes, int n_in,
                              void* d_out, int out_size, void* d_ws, size_t ws_size,
                              hipStream_t stream) {
    (void)in_sizes; (void)n_in; (void)out_size;
    const float* h = (const float*)d_in[0];
    const float* x = (const float*)d_in[1];
    const float* B = (const float*)d_in[2];
    float* y = (float*)d_out;

    const size_t need = (size_t)(DCH * NHALF + DCH) * sizeof(float2);
    if (ws_size >= need && d_ws != nullptr) {
        (void)hipFuncSetAttribute((const void*)hspec_kernel,
                                  hipFuncAttributeMaxDynamicSharedMemorySize,
                                  LDSE * (int)sizeof(float2));
        (void)hipFuncSetAttribute((const void*)fftconv_main,
                                  hipFuncAttributeMaxDynamicSharedMemorySize,
                                  LDSE * (int)sizeof(float2));
        float* wsHf = (float*)d_ws;
        float* wsNy = wsHf + 2 * (size_t)DCH * NHALF;
        hspec_kernel<<<dim3(DCH), dim3(NTH), LDSE * sizeof(float2), stream>>>(h, B, wsHf, wsNy);
        fftconv_main<<<dim3(4 * DCH), dim3(NTH), LDSE * sizeof(float2), stream>>>(x, wsHf, wsNy, y);
    } else {
        (void)hipFuncSetAttribute((const void*)fftconv_v2,
                                  hipFuncAttributeMaxDynamicSharedMemorySize,
                                  LDSE2 * (int)sizeof(float2));
        fftconv_v2<<<dim3(4 * DCH), dim3(NTH2), LDSE2 * sizeof(float2), stream>>>(h, x, B, y);
    }
}

// Round 5
// 129.798 us; speedup vs baseline: 4.0084x; 1.0775x over previous
//
#include <hip/hip_runtime.h>

#define DCH   768
#define NHALF 8192
#define NTH   512
#define PHYS(i) ((i) + ((i) >> 4))
#define LDSE  (NHALF + NHALF / 16)     // 8704 float2 = 69632 B
#define NFULL 16384
#define NTH2  1024
#define LDSE2 (NFULL + NFULL / 16)     // 17408 float2 = 139264 B

#define C1F 0.9238795325112867f        // cos(pi/8)
#define S1F 0.3826834323650898f        // sin(pi/8)
#define C2F 0.7071067811865476f        // cos(pi/4)

typedef float v2f __attribute__((ext_vector_type(2)));

__device__ __forceinline__ v2f mk(float x, float y) { v2f r; r.x = x; r.y = y; return r; }
// complex multiply: 2 packed ops (v_pk_mul_f32 + v_pk_fma_f32 w/ neg_lo)
__device__ __forceinline__ v2f cmul(v2f a, v2f b) {
    v2f re = a.xx * b;                       // {ax*bx, ax*by}
    return __builtin_elementwise_fma(mk(-a.y, a.y), mk(b.y, b.x), re);
}
__device__ __forceinline__ v2f mnegi(v2f t) { return mk(t.y, -t.x); }   // -i*t
__device__ __forceinline__ v2f wtw(float rev) {   // e^{2*pi*i*rev}
    return mk(__builtin_amdgcn_cosf(rev), __builtin_amdgcn_sinf(rev));
}
__device__ __forceinline__ int drev8(int v) {        // 4-digit base-4 reversal of 8-bit
    return ((v & 3) << 6) | ((v & 12) << 2) | ((v >> 2) & 12) | ((v >> 6) & 3);
}
__device__ __forceinline__ constexpr int rev2i(int a) { return ((a & 3) << 2) | ((a >> 2) & 3); }
__device__ __forceinline__ constexpr int rtof(int t)  { return ((t & 3) << 2) | (t >> 2); }

__device__ __forceinline__ v2f Ktw(int rt) {      // e^{-2*pi*i*rt/32}
    const float KC[16] = {1.0f, 0.980785280f, 0.923879533f, 0.831469612f,
                          0.707106781f, 0.555570233f, 0.382683432f, 0.195090322f,
                          0.0f, -0.195090322f, -0.382683432f, -0.555570233f,
                          -0.707106781f, -0.831469612f, -0.923879533f, -0.980785280f};
    const float KS[16] = {0.0f, -0.195090322f, -0.382683432f, -0.555570233f,
                          -0.707106781f, -0.831469612f, -0.923879533f, -0.980785280f,
                          -1.0f, -0.980785280f, -0.923879533f, -0.831469612f,
                          -0.707106781f, -0.555570233f, -0.382683432f, -0.195090322f};
    return mk(KC[rt], KS[rt]);
}

// -------- fused radix-16 DIF (levels m1=4*m2 then m2); r1 = -j/(16*m2)
__device__ __forceinline__ void dif16(v2f* a, float r1) {
    const v2f w10 = wtw(r1);
    const v2f sq  = cmul(w10, w10);
    const v2f cu  = cmul(sq, w10);
#pragma unroll
    for (int ai = 0; ai < 4; ++ai) {
        v2f w1, w2, w3;
        if (ai == 0)      { w1 = w10; w2 = sq; w3 = cu; }
        else if (ai == 1) { w1 = cmul(w10, mk(C1F, -S1F));
                            w2 = cmul(sq,  mk(C2F, -C2F));
                            w3 = cmul(cu,  mk(S1F, -C1F)); }
        else if (ai == 2) { w1 = cmul(w10, mk(C2F, -C2F));
                            w2 = mk(sq.y, -sq.x);           // sq * (-i)
                            w3 = cmul(cu,  mk(-C2F, -C2F)); }
        else              { w1 = cmul(w10, mk(S1F, -C1F));
                            w2 = cmul(sq,  mk(-C2F, -C2F));
                            w3 = cmul(cu,  mk(-C1F,  S1F)); }
        v2f u0 = a[ai], u1 = a[ai + 4], u2 = a[ai + 8], u3 = a[ai + 12];
        v2f t0 = u0 + u2, t1 = u1 + u3;
        v2f t2 = u0 - u2, t3 = u1 - u3;
        v2f mi3 = mnegi(t3);
        a[ai]      = t0 + t1;
        a[ai + 4]  = cmul(t2 + mi3, w1);
        a[ai + 8]  = cmul(t0 - t1, w2);
        a[ai + 12] = cmul(t2 - mi3, w3);
    }
    const v2f v1 = cmul(sq, sq);                  // w10^4
    const v2f v2 = cmul(v1, v1);
    const v2f v3 = cmul(v2, v1);
#pragma unroll
    for (int p = 0; p < 4; ++p) {
        v2f u0 = a[4 * p], u1 = a[4 * p + 1], u2 = a[4 * p + 2], u3 = a[4 * p + 3];
        v2f t0 = u0 + u2, t1 = u1 + u3;
        v2f t2 = u0 - u2, t3 = u1 - u3;
        v2f mi3 = mnegi(t3);
        a[4 * p]     = t0 + t1;
        a[4 * p + 1] = cmul(t2 + mi3, v1);
        a[4 * p + 2] = cmul(t0 - t1, v2);
        a[4 * p + 3] = cmul(t2 - mi3, v3);
    }
}
// -------- fused inverse radix-16 (levels m2 then m1=4*m2); r1 = +j/(16*m2)
__device__ __forceinline__ void dit16(v2f* a, float r1) {
    const v2f w10 = wtw(r1);
    const v2f sq  = cmul(w10, w10);
    const v2f cu  = cmul(sq, w10);
    const v2f v1  = cmul(sq, sq);
    const v2f v2  = cmul(v1, v1);
    const v2f v3  = cmul(v2, v1);
#pragma unroll
    for (int p = 0; p < 4; ++p) {
        v2f b0 = a[4 * p];
        v2f b1 = cmul(a[4 * p + 1], v1);
        v2f b2 = cmul(a[4 * p + 2], v2);
        v2f b3 = cmul(a[4 * p + 3], v3);
        v2f t0 = b0 + b2, t1 = b0 - b2;
        v2f t2 = b1 + b3;
        v2f dd = b3 - b1;
        v2f t3 = mnegi(dd);
        a[4 * p]     = t0 + t2;
        a[4 * p + 1] = t1 + t3;
        a[4 * p + 2] = t0 - t2;
        a[4 * p + 3] = t1 - t3;
    }
#pragma unroll
    for (int ai = 0; ai < 4; ++ai) {
        v2f w1, w2, w3;
        if (ai == 0)      { w1 = w10; w2 = sq; w3 = cu; }
        else if (ai == 1) { w1 = cmul(w10, mk(C1F, S1F));
                            w2 = cmul(sq,  mk(C2F, C2F));
                            w3 = cmul(cu,  mk(S1F, C1F)); }
        else if (ai == 2) { w1 = cmul(w10, mk(C2F, C2F));
                            w2 = mk(-sq.y, sq.x);           // sq * (+i)
                            w3 = cmul(cu,  mk(-C2F, C2F)); }
        else              { w1 = cmul(w10, mk(S1F, C1F));
                            w2 = cmul(sq,  mk(-C2F, C2F));
                            w3 = cmul(cu,  mk(-C1F, -S1F)); }
        v2f b0 = a[ai];
        v2f b1 = cmul(a[ai + 4], w1);
        v2f b2 = cmul(a[ai + 8], w2);
        v2f b3 = cmul(a[ai + 12], w3);
        v2f t0 = b0 + b2, t1 = b0 - b2;
        v2f t2 = b1 + b3;
        v2f dd = b3 - b1;
        v2f t3 = mnegi(dd);
        a[ai]      = t0 + t2;
        a[ai + 4]  = t1 + t3;
        a[ai + 8]  = t0 - t2;
        a[ai + 12] = t1 - t3;
    }
}
__device__ __forceinline__ void fwd4x4(v2f* a) {   // radix-4 DIF, m=1, twiddle-free
#pragma unroll
    for (int u = 0; u < 4; ++u) {
        v2f u0 = a[4*u], u1 = a[4*u+1], u2 = a[4*u+2], u3 = a[4*u+3];
        v2f t0 = u0 + u2, t1 = u1 + u3, t2 = u0 - u2, t3 = u1 - u3;
        v2f mi3 = mnegi(t3);
        a[4*u] = t0 + t1; a[4*u+1] = t2 + mi3;
        a[4*u+2] = t0 - t1; a[4*u+3] = t2 - mi3;
    }
}
__device__ __forceinline__ void inv4x4(v2f* a) {   // inverse radix-4, m=1
#pragma unroll
    for (int u = 0; u < 4; ++u) {
        v2f b0 = a[4*u], b1 = a[4*u+1], b2 = a[4*u+2], b3 = a[4*u+3];
        v2f t0 = b0 + b2, t1 = b0 - b2, t2 = b1 + b3;
        v2f dd = b3 - b1;
        v2f t3 = mnegi(dd);
        a[4*u] = t0 + t2; a[4*u+1] = t1 + t3;
        a[4*u+2] = t0 - t2; a[4*u+3] = t1 - t3;
    }
}

// Forward 8192-pt complex FFT of src (4096 nonzero v2f, top half zero).
__device__ __forceinline__ void fwd8k(const v2f* __restrict__ src,
                                      v2f* __restrict__ z, const int w, v2f* a) {
    const float R2 = 0.70710678118654752f;
    // ---- P1: radix-2(m=4096, top half zero) + radix-4(m=1024) from global
#pragma unroll
    for (int g = 0; g < 2; ++g) {
        const int i0 = w + 512 * g;
        v2f c0 = src[i0], c1 = src[i0 + 1024], c2 = src[i0 + 2048], c3 = src[i0 + 3072];
        const v2f wA  = wtw(-(float)i0 * (1.0f / 8192.0f));
        const v2f wB  = cmul(wA, wA);
        const v2f wB2 = cmul(wB, wB);
        const v2f wB3 = cmul(wB2, wB);
        const int pb = PHYS(i0);
        v2f t0 = c0 + c2, t1 = c1 + c3, t2 = c0 - c2, t3 = c1 - c3;
        v2f mi3 = mnegi(t3);
        z[pb]            = t0 + t1;
        z[pb + 1088]     = cmul(t2 + mi3, wB);
        z[pb + 2 * 1088] = cmul(t0 - t1, wB2);
        z[pb + 3 * 1088] = cmul(t2 - mi3, wB3);
        v2f d0 = cmul(c0, wA);
        v2f d1 = cmul(c1, cmul(wA, mk(R2, -R2)));
        v2f d2 = cmul(c2, mk(wA.y, -wA.x));           // -i*wA
        v2f d3 = cmul(c3, cmul(wA, mk(-R2, -R2)));
        t0 = d0 + d2; t1 = d1 + d3; t2 = d0 - d2; t3 = d1 - d3;
        mi3 = mnegi(t3);
        z[pb + 4 * 1088] = t0 + t1;
        z[pb + 5 * 1088] = cmul(t2 + mi3, wB);
        z[pb + 6 * 1088] = cmul(t0 - t1, wB2);
        z[pb + 7 * 1088] = cmul(t2 - mi3, wB3);
    }
    __syncthreads();
    // ---- P2: radix-16, m2 = 64
    {
        const int j = w & 63, blk = w >> 6;
        const int base = PHYS(blk * 1024 + j);
#pragma unroll
        for (int t = 0; t < 16; ++t) a[t] = z[base + 68 * t];
        dif16(a, -(float)j * (1.0f / 1024.0f));
#pragma unroll
        for (int t = 0; t < 16; ++t) z[base + 68 * t] = a[t];
    }
    __syncthreads();
    // ---- P3: radix-16, m2 = 4
    {
        const int j = w & 3, g = w >> 2;
        const int i0 = g * 64 + j;
#pragma unroll
        for (int t = 0; t < 16; ++t) a[t] = z[PHYS(i0 + 4 * t)];
        dif16(a, -(float)j * (1.0f / 64.0f));
#pragma unroll
        for (int t = 0; t < 16; ++t) z[PHYS(i0 + 4 * t)] = a[t];
    }
    __syncthreads();
    // ---- P4a: final radix-4 (m=1) in regs, publish C
    {
        const int base = 17 * w;
#pragma unroll
        for (int t = 0; t < 16; ++t) a[t] = z[base + t];
        fwd4x4(a);
#pragma unroll
        for (int t = 0; t < 16; ++t) z[base + t] = a[t];
    }
    __syncthreads();
}

// ============ kernel 1: per-channel H spectrum, scaled by 1/N, H += B
extern "C" __global__ void __launch_bounds__(NTH, 4)
hspec_kernel(const float* __restrict__ hg, const float* __restrict__ bg,
             float* __restrict__ wsHf, float* __restrict__ wsNy) {
    extern __shared__ v2f z[];
    const int w = threadIdx.x;
    const int d = blockIdx.x;
    const v2f* hr = (const v2f*)hg + (size_t)d * 4096;
    v2f a[16];
    fwd8k(hr, z, w, a);

    const float Bd = bg[d];
    const float invN = 1.0f / 16384.0f;
    v2f* out = (v2f*)wsHf + (size_t)d * NHALF;
    const int wm = w & 255, whi = w >> 8;
    const int k0 = 2 * drev8(wm) + whi;
    const v2f wk0 = wtw(-(float)k0 * (1.0f / 16384.0f));
    int qm = 0;
    if (w != 0) { const int bq = (512 - k0) >> 1; qm = (whi << 8) | drev8(bq); }
#pragma unroll
    for (int t = 0; t < 16; ++t) {
        const int rt = rtof(t);
        if (w == 0 && t == 0) {
            v2f C0 = a[0];
            out[0] = mk((C0.x + C0.y + Bd) * invN, 0.0f);
            ((v2f*)wsNy)[d] = mk((C0.x - C0.y + Bd) * invN, 0.0f);
        } else {
            const int cq = (w == 0) ? rev2i(16 - rt) : rev2i(15 - rt);
            const v2f Cq = z[17 * qm + cq];
            const v2f Cp = a[t];
            const v2f cA = mk(0.5f * (Cp.x + Cq.x), 0.5f * (Cp.y - Cq.y));
            const v2f cB = mk(0.5f * (Cp.y + Cq.y), -0.5f * (Cp.x - Cq.x));
            const v2f Wk = cmul(wk0, Ktw(rt));
            const v2f Hf = cA + cmul(Wk, cB);
            out[(t << 9) + w] = mk((Hf.x + Bd) * invN, Hf.y * invN);
        }
    }
}

// ============ kernel 2: main conv
extern "C" __global__ void __launch_bounds__(NTH, 4)
fftconv_main(const float* __restrict__ xg, const float* __restrict__ wsHf,
             const float* __restrict__ wsNy, float* __restrict__ yg) {
    extern __shared__ v2f z[];
    const int w = threadIdx.x;
    const int bid = blockIdx.x;
    const int d = bid >> 2, b = bid & 3;
    const v2f* xr = (const v2f*)xg + (size_t)(b * DCH + d) * 4096;
    const v2f* hrow = (const v2f*)wsHf + (size_t)d * NHALF;
    const float R2 = 0.70710678118654752f;
    v2f a[16];
    fwd8k(xr, z, w, a);

    // ---- P4b: pair-owner combine; owner Wtil stays in regs, partner to LDS
    {
        const int wm = w & 255, whi = w >> 8;
        const int k0 = 2 * drev8(wm) + whi;
        const v2f wk0 = wtw(-(float)k0 * (1.0f / 16384.0f));
        int qm = 0;
        if (w != 0) { const int bq = (512 - k0) >> 1; qm = (whi << 8) | drev8(bq); }
#pragma unroll
        for (int t = 0; t < 16; ++t) {
            if ((t & 3) > 1) continue;           // owner elements: rt < 8
            const int rt = rtof(t);
            if (w == 0 && t == 0) {
                v2f C0 = a[0];
                float X0 = C0.x + C0.y, XN = C0.x - C0.y;
                v2f H0 = hrow[0];
                v2f HN = ((const v2f*)wsNy)[d];
                v2f Y1 = mk(X0 * H0.x, X0 * H0.y);
                v2f Y2 = mk(XN * HN.x, XN * HN.y);
                v2f S  = mk(Y1.x + Y2.x, Y1.y - Y2.y);
                v2f Dd = mk(Y1.x - Y2.x, Y1.y + Y2.y);
                a[0] = mk(S.x - Dd.y, S.y + Dd.x);
            } else {
                const int cq = (w == 0) ? rev2i(16 - rt) : rev2i(15 - rt);
                const v2f Cq = z[17 * qm + cq];
                const v2f Cp = a[t];
                const v2f cA = mk(0.5f * (Cp.x + Cq.x), 0.5f * (Cp.y - Cq.y));
                const v2f cB = mk(0.5f * (Cp.y + Cq.y), -0.5f * (Cp.x - Cq.x));
                const v2f Wk = cmul(wk0, Ktw(rt));
                const v2f T  = cmul(Wk, cB);
                const v2f X1 = cA + T;
                const v2f X2 = mk(cA.x - T.x, -(cA.y - T.y));  // conj(cA - T)
                const v2f Hp = hrow[(t << 9) + w];
                const v2f Hq = hrow[(cq << 9) + qm];
                const v2f Y1 = cmul(X1, Hp);
                const v2f Y2 = cmul(X2, Hq);
                const v2f S  = mk(Y1.x + Y2.x, Y1.y - Y2.y);
                const v2f Dd = mk(Y1.x - Y2.x, Y1.y + Y2.y);
                const v2f Vk = mk(Wk.x, -Wk.y);
                const v2f U  = cmul(Vk, Dd);
                a[t]            = mk(S.x - U.y, S.y + U.x);     // own Wtil[k]
                z[17 * qm + cq] = mk(S.x + U.y, U.x - S.y);     // partner Wtil
            }
        }
        if (w == 0) {   // self-pair k = 4096 (position 2)
            const v2f Cp = z[2];
            const v2f cA = mk(Cp.x, 0.0f);
            const v2f cB = mk(Cp.y, 0.0f);
            const v2f Wk = mk(0.0f, -1.0f);
            const v2f T  = cmul(Wk, cB);
            const v2f X1 = cA + T;
            const v2f X2 = mk(cA.x - T.x, -(cA.y - T.y));
            const v2f Hp = hrow[(2 << 9)];
            const v2f Y1 = cmul(X1, Hp);
            const v2f Y2 = cmul(X2, Hp);
            const v2f S  = mk(Y1.x + Y2.x, Y1.y - Y2.y);
            const v2f Dd = mk(Y1.x - Y2.x, Y1.y + Y2.y);
            const v2f Vk = mk(0.0f, 1.0f);
            const v2f U  = cmul(Vk, Dd);
            z[2] = mk(S.x - U.y, S.y + U.x);
        }
    }
    __syncthreads();
    // ---- inverse radix-4 (m=1): own 8 from regs, missing 8 from LDS
    {
        const int base = 17 * w;
#pragma unroll
        for (int t = 0; t < 16; ++t)
            if ((t & 3) > 1) a[t] = z[base + t];
        inv4x4(a);
#pragma unroll
        for (int t = 0; t < 16; ++t) z[base + t] = a[t];
    }
    __syncthreads();
    // ---- P5: inverse radix-16, m2 = 4
    {
        const int j = w & 3, g = w >> 2;
        const int i0 = g * 64 + j;
#pragma unroll
        for (int t = 0; t < 16; ++t) a[t] = z[PHYS(i0 + 4 * t)];
        dit16(a, (float)j * (1.0f / 64.0f));
#pragma unroll
        for (int t = 0; t < 16; ++t) z[PHYS(i0 + 4 * t)] = a[t];
    }
    __syncthreads();
    // ---- P6: inverse radix-16, m2 = 64
    {
        const int j = w & 63, blk = w >> 6;
        const int base = PHYS(blk * 1024 + j);
#pragma unroll
        for (int t = 0; t < 16; ++t) a[t] = z[base + 68 * t];
        dit16(a, (float)j * (1.0f / 1024.0f));
#pragma unroll
        for (int t = 0; t < 16; ++t) z[base + 68 * t] = a[t];
    }
    __syncthreads();
    // ---- P7: inverse radix-4(m=1024) + inverse radix-2(m=4096), store y
    {
        v2f* yr = (v2f*)yg + (size_t)(b * DCH + d) * 4096;
#pragma unroll
        for (int g = 0; g < 2; ++g) {
            const int i0 = w + 512 * g;
            const int pb = PHYS(i0);
            v2f q0 = z[pb],            q1 = z[pb + 1088],
                q2 = z[pb + 2 * 1088], q3 = z[pb + 3 * 1088],
                q4 = z[pb + 4 * 1088], q5 = z[pb + 5 * 1088],
                q6 = z[pb + 6 * 1088], q7 = z[pb + 7 * 1088];
            const v2f vA  = wtw((float)i0 * (1.0f / 8192.0f));
            const v2f vB  = cmul(vA, vA);
            const v2f vB2 = cmul(vB, vB);
            const v2f vB3 = cmul(vB2, vB);
            v2f b1 = cmul(q1, vB), b2 = cmul(q2, vB2), b3 = cmul(q3, vB3);
            v2f t0 = q0 + b2, t1 = q0 - b2, t2 = b1 + b3;
            v2f dd = b3 - b1;
            v2f t3 = mnegi(dd);
            v2f T0 = t0 + t2, T1 = t1 + t3, T2 = t0 - t2, T3 = t1 - t3;
            b1 = cmul(q5, vB); b2 = cmul(q6, vB2); b3 = cmul(q7, vB3);
            t0 = q4 + b2; t1 = q4 - b2; t2 = b1 + b3;
            dd = b3 - b1;
            t3 = mnegi(dd);
            v2f B0 = t0 + t2, B1 = t1 + t3, B2 = t0 - t2, B3 = t1 - t3;
            yr[i0]        = T0 + cmul(B0, vA);
            yr[i0 + 1024] = T1 + cmul(B1, cmul(vA, mk(R2, R2)));
            yr[i0 + 2048] = T2 + cmul(B2, mk(-vA.y, vA.x));   // i*vA
            yr[i0 + 3072] = T3 + cmul(B3, cmul(vA, mk(-R2, R2)));
        }
    }
}

// ===================== fallback: 16K-FFT single-kernel path =====================
__device__ __forceinline__ int drev14(int v) {
    int r = 0;
#pragma unroll
    for (int i = 0; i < 7; ++i) { r = (r << 2) | (v & 3); v >>= 2; }
    return r;
}
__device__ __forceinline__ int drev10(int v) {
    int r = 0;
#pragma unroll
    for (int i = 0; i < 5; ++i) { r = (r << 2) | (v & 3); v >>= 2; }
    return r;
}

extern "C" __global__ void __launch_bounds__(NTH2, 4)
fftconv_v2(const float* __restrict__ hg, const float* __restrict__ xg,
           const float* __restrict__ bg, float* __restrict__ yg) {
    extern __shared__ v2f z[];
    const int w = threadIdx.x;
    const int bid = blockIdx.x;
    const int d = bid >> 2, b = bid & 3;
    const float* xr = xg + (size_t)(b * DCH + d) * 8192;
    const float* hr = hg + (size_t)d * 8192;
    v2f a[16];
    float xv[8];
    {
#pragma unroll
        for (int t = 0; t < 8; ++t) {
            xv[t] = xr[w + 1024 * t];
            float hv = hr[w + 1024 * t];
            a[t] = mk(xv[t], hv);
        }
        const float r1 = -(float)w * (1.0f / 16384.0f);
#pragma unroll
        for (int ai = 0; ai < 4; ++ai) {
            v2f u0 = a[ai], u1 = a[ai + 4];
            v2f mi3 = mk(u1.y, -u1.x);
            v2f w1 = wtw(r1 - 0.0625f * ai);
            v2f w2 = cmul(w1, w1), w3 = cmul(w2, w1);
            a[ai]      = u0 + u1;
            a[ai + 4]  = cmul(u0 + mi3, w1);
            a[ai + 8]  = cmul(u0 - u1, w2);
            a[ai + 12] = cmul(u0 - mi3, w3);
        }
        v2f v1 = wtw(4.0f * r1);
        v2f v2 = cmul(v1, v1), v3 = cmul(v2, v1);
#pragma unroll
        for (int p = 0; p < 4; ++p) {
            v2f u0 = a[4 * p], u1 = a[4 * p + 1], u2 = a[4 * p + 2], u3 = a[4 * p + 3];
            v2f t0 = u0 + u2, t1 = u1 + u3;
            v2f t2 = u0 - u2, t3 = u1 - u3;
            v2f mi3 = mnegi(t3);
            a[4 * p]     = t0 + t1;
            a[4 * p + 1] = cmul(t2 + mi3, v1);
            a[4 * p + 2] = cmul(t0 - t1, v2);
            a[4 * p + 3] = cmul(t2 - mi3, v3);
        }
        const int base = PHYS(w);
#pragma unroll
        for (int t = 0; t < 16; ++t) z[base + 1088 * t] = a[t];
    }
    __syncthreads();
    {
        const int j = w & 63, grp = w >> 6;
        const int base = PHYS(grp * 1024 + j);
#pragma unroll
        for (int t = 0; t < 16; ++t) a[t] = z[base + 68 * t];
        dif16(a, -(float)j * (1.0f / 1024.0f));
#pragma unroll
        for (int t = 0; t < 16; ++t) z[base + 68 * t] = a[t];
    }
    __syncthreads();
    {
        const int j = w & 3, grp = w >> 2;
        const int i0 = grp * 64 + j;
#pragma unroll
        for (int t = 0; t < 16; ++t) a[t] = z[PHYS(i0 + 4 * t)];
        dif16(a, -(float)j * (1.0f / 64.0f));
#pragma unroll
        for (int t = 0; t < 16; ++t) z[PHYS(i0 + 4 * t)] = a[t];
    }
    __syncthreads();
    {
        const int base = 17 * w;
#pragma unroll
        for (int t = 0; t < 16; ++t) a[t] = z[base + t];
        fwd4x4(a);
#pragma unroll
        for (int t = 0; t < 16; ++t) z[base + t] = a[t];
        __syncthreads();
        const int kw = drev10(w);
#pragma unroll
        for (int t = 0; t < 16; ++t) {
            const int rt = (((t & 3) << 2) | (t >> 2));
            const int k = (rt << 10) | kw;
            const int pp = drev14(16384 - k);
            const v2f Zm = z[PHYS(pp)];
            const v2f Zp = a[t];
            const v2f A  = mk(Zp.x + Zm.x, Zp.y - Zm.y);
            const v2f Dv = mk(Zp.x - Zm.x, Zp.y + Zm.y);
            const v2f X  = mk(0.5f * A.x, 0.5f * A.y);
            const v2f H  = mk(0.5f * Dv.y, -0.5f * Dv.x);
            a[t] = cmul(X, H);
        }
        __syncthreads();
        inv4x4(a);
#pragma unroll
        for (int t = 0; t < 16; ++t) z[base + t] = a[t];
    }
    __syncthreads();
    {
        const int j = w & 3, grp = w >> 2;
        const int i0 = grp * 64 + j;
#pragma unroll
        for (int t = 0; t < 16; ++t) a[t] = z[PHYS(i0 + 4 * t)];
        dit16(a, (float)j * (1.0f / 64.0f));
#pragma unroll
        for (int t = 0; t < 16; ++t) z[PHYS(i0 + 4 * t)] = a[t];
    }
    __syncthreads();
    {
        const int j = w & 63, grp = w >> 6;
        const int base = PHYS(grp * 1024 + j);
#pragma unroll
        for (int t = 0; t < 16; ++t) a[t] = z[base + 68 * t];
        dit16(a, (float)j * (1.0f / 1024.0f));
#pragma unroll
        for (int t = 0; t < 16; ++t) z[base + 68 * t] = a[t];
    }
    __syncthreads();
    {
        const int base = PHYS(w);
#pragma unroll
        for (int t = 0; t < 16; ++t) a[t] = z[base + 1088 * t];
        const float r1 = (float)w * (1.0f / 16384.0f);
        v2f v1 = wtw(4.0f * r1);
        v2f v2 = cmul(v1, v1), v3 = cmul(v2, v1);
#pragma unroll
        for (int p = 0; p < 4; ++p) {
            v2f b0 = a[4 * p];
            v2f b1 = cmul(a[4 * p + 1], v1);
            v2f b2 = cmul(a[4 * p + 2], v2);
            v2f b3 = cmul(a[4 * p + 3], v3);
            v2f t0 = b0 + b2, t1 = b0 - b2;
            v2f t2 = b1 + b3;
            v2f dd = b3 - b1;
            v2f t3 = mnegi(dd);
            a[4 * p]     = t0 + t2;
            a[4 * p + 1] = t1 + t3;
            a[4 * p + 2] = t0 - t2;
            a[4 * p + 3] = t1 - t3;
        }
        const float bd = bg[d];
        const float invN = 1.0f / 16384.0f;
#pragma unroll
        for (int ai = 0; ai < 4; ++ai) {
            v2f w1 = wtw(r1 + 0.0625f * ai);
            v2f w2 = cmul(w1, w1), w3 = cmul(w2, w1);
            v2f b0 = a[ai];
            v2f vv1 = cmul(a[ai + 4], w1);
            v2f vv2 = cmul(a[ai + 8], w2);
            v2f vv3 = cmul(a[ai + 12], w3);
            v2f t0 = b0 + vv2, t1 = b0 - vv2;
            v2f t2 = vv1 + vv3;
            v2f dd = vv3 - vv1;
            v2f t3 = mnegi(dd);
            v2f o0 = t0 + t2;
            v2f o1 = t1 + t3;
            yg[(size_t)(b * DCH + d) * 8192 + w + 1024 * ai]        = fmaf(xv[ai], bd, o0.x * invN);
            yg[(size_t)(b * DCH + d) * 8192 + w + 4096 + 1024 * ai] = fmaf(xv[ai + 4], bd, o1.x * invN);
        }
    }
}

extern "C" void kernel_launch(void* const* d_in, const int* in_sizes, int n_in,
                              void* d_out, int out_size, void* d_ws, size_t ws_size,
                              hipStream_t stream) {
    (void)in_sizes; (void)n_in; (void)out_size;
    const float* h = (const float*)d_in[0];
    const float* x = (const float*)d_in[1];
    const float* B = (const float*)d_in[2];
    float* y = (float*)d_out;

    const size_t need = (size_t)(DCH * NHALF + DCH) * sizeof(float2);
    if (ws_size >= need && d_ws != nullptr) {
        (void)hipFuncSetAttribute((const void*)hspec_kernel,
                                  hipFuncAttributeMaxDynamicSharedMemorySize,
                                  LDSE * (int)sizeof(float2));
        (void)hipFuncSetAttribute((const void*)fftconv_main,
                                  hipFuncAttributeMaxDynamicSharedMemorySize,
                                  LDSE * (int)sizeof(float2));
        float* wsHf = (float*)d_ws;
        float* wsNy = wsHf + 2 * (size_t)DCH * NHALF;
        hspec_kernel<<<dim3(DCH), dim3(NTH), LDSE * sizeof(float2), stream>>>(h, B, wsHf, wsNy);
        fftconv_main<<<dim3(4 * DCH), dim3(NTH), LDSE * sizeof(float2), stream>>>(x, wsHf, wsNy, y);
    } else {
        (void)hipFuncSetAttribute((const void*)fftconv_v2,
                                  hipFuncAttributeMaxDynamicSharedMemorySize,
                                  LDSE2 * (int)sizeof(float2));
        fftconv_v2<<<dim3(4 * DCH), dim3(NTH2), LDSE2 * sizeof(float2), stream>>>(h, x, B, y);
    }
}